// Round 1
// baseline (5187.460 us; speedup 1.0000x reference)
//
#include <hip/hip_runtime.h>
#include <hip/hip_bf16.h>
#include <math.h>

// Problem constants
#define NB   2        // batch N
#define CH   128      // C
#define HT   64
#define WD   64
#define HW   4096     // H*W
#define TF   7        // frames
#define LSEQ 28672    // 7*4096
#define NCHUNK 128    // mamba scan chunks (per batch)
#define LCHUNK 224    // 128*224 = 28672

typedef long long i64;

static inline int cdiv(i64 a, int b) { return (int)((a + b - 1) / b); }

__device__ __forceinline__ float lrelu_f(float v) { return v >= 0.f ? v : 0.1f * v; }

// ---------------------------------------------------------------- transpose
__global__ void transpose_k(const float* __restrict__ src, float* __restrict__ dst, int R, int Cc) {
    i64 idx = (i64)blockIdx.x * blockDim.x + threadIdx.x;
    if (idx >= (i64)R * Cc) return;
    int r = (int)(idx / Cc), c = (int)(idx - (i64)r * Cc);
    dst[(i64)c * R + r] = src[idx];
}

// ---------------------------------------------------------------- generic 3x3 conv, pad=1
// tile 16x16 pixels, 16 output channels per block, Cin chunked by 16.
__global__ __launch_bounds__(256) void conv3x3_k(
    const float* __restrict__ in1, int Cin1, i64 in1_bs,
    const float* __restrict__ in2, int Cin2, i64 in2_bs,
    const float* __restrict__ w, const float* __restrict__ bias, int Cout,
    int H, int W,
    const float* __restrict__ res, i64 res_bs,
    float* __restrict__ out, i64 out_bs, int relu)
{
    __shared__ float s_in[16][18][18];
    __shared__ float s_w[16][9][16];   // [ci][k][co]
    const int tid = threadIdx.x;
    const int tx = tid & 15, ty = tid >> 4;
    const int tX = W >> 4;
    const int tx0 = (blockIdx.x % tX) << 4, ty0 = (blockIdx.x / tX) << 4;
    const int co0 = blockIdx.y << 4;
    const int z = blockIdx.z;
    const int CinT = Cin1 + Cin2;
    const i64 hw = (i64)H * W;

    float acc[16];
#pragma unroll
    for (int i = 0; i < 16; ++i) acc[i] = 0.f;

    for (int ci0 = 0; ci0 < CinT; ci0 += 16) {
        for (int idx = tid; idx < 16 * 324; idx += 256) {
            int chn = idx / 324; int r = idx - chn * 324;
            int iy = r / 18; int ix = r - iy * 18;
            int gy = ty0 + iy - 1, gx = tx0 + ix - 1;
            int ci = ci0 + chn;
            float v = 0.f;
            if (ci < CinT && gy >= 0 && gy < H && gx >= 0 && gx < W) {
                if (ci < Cin1) v = in1[(i64)z * in1_bs + (i64)ci * hw + gy * W + gx];
                else           v = in2[(i64)z * in2_bs + (i64)(ci - Cin1) * hw + gy * W + gx];
            }
            s_in[chn][iy][ix] = v;
        }
        for (int idx = tid; idx < 16 * 144; idx += 256) {
            int co = idx / 144; int r = idx - co * 144;
            int ci = r / 9; int k = r - ci * 9;
            float v = 0.f;
            int gco = co0 + co, gci = ci0 + ci;
            if (gco < Cout && gci < CinT) v = w[((i64)gco * CinT + gci) * 9 + k];
            s_w[ci][k][co] = v;
        }
        __syncthreads();
#pragma unroll 2
        for (int ci = 0; ci < 16; ++ci) {
#pragma unroll
            for (int ky = 0; ky < 3; ++ky) {
#pragma unroll
                for (int kx = 0; kx < 3; ++kx) {
                    float xv = s_in[ci][ty + ky][tx + kx];
                    const float4* wr = (const float4*)(&s_w[ci][ky * 3 + kx][0]);
                    float wv[16];
                    ((float4*)wv)[0] = wr[0];
                    ((float4*)wv)[1] = wr[1];
                    ((float4*)wv)[2] = wr[2];
                    ((float4*)wv)[3] = wr[3];
#pragma unroll
                    for (int co = 0; co < 16; ++co) acc[co] = fmaf(wv[co], xv, acc[co]);
                }
            }
        }
        __syncthreads();
    }
    int y = ty0 + ty, x = tx0 + tx;
#pragma unroll
    for (int co = 0; co < 16; ++co) {
        int gco = co0 + co;
        if (gco < Cout) {
            float v = acc[co] + bias[gco];
            if (relu) v = lrelu_f(v);
            if (res) v += res[(i64)z * res_bs + (i64)gco * hw + y * W + x];
            out[(i64)z * out_bs + (i64)gco * hw + y * W + x] = v;
        }
    }
}

// ---------------------------------------------------------------- spynet helpers
__global__ void copy_pyr_k(const float* __restrict__ lqs, float* __restrict__ dst, int shift) {
    int idx = blockIdx.x * blockDim.x + threadIdx.x;
    if (idx >= 12 * 3 * HW) return;
    int p = idx & 4095; int rest = idx >> 12; int c = rest % 3; int bf = rest / 3;
    int b = bf / 6, i = bf % 6;
    dst[idx] = lqs[(((i64)b * 7 + i + shift) * 3 + c) * HW + p];
}

__global__ void avgpool_k(const float* __restrict__ in, float* __restrict__ out, int nc, int hi, int wi) {
    int ho = hi >> 1, wo = wi >> 1;
    int idx = blockIdx.x * blockDim.x + threadIdx.x;
    if (idx >= nc * ho * wo) return;
    int x = idx % wo; int y = (idx / wo) % ho; int c = idx / (wo * ho);
    const float* ip = in + (i64)c * hi * wi;
    out[idx] = 0.25f * (ip[(2 * y) * wi + 2 * x] + ip[(2 * y) * wi + 2 * x + 1] +
                        ip[(2 * y + 1) * wi + 2 * x] + ip[(2 * y + 1) * wi + 2 * x + 1]);
}

// inp = concat([a, warp(b2, flow), flow]) channels 3+3+2
__global__ void build_inp_k(const float* __restrict__ a, const float* __restrict__ b2,
                            const float* __restrict__ flow, float* __restrict__ inp, int hl, int wl) {
    int idx = blockIdx.x * blockDim.x + threadIdx.x;
    int hw = hl * wl;
    if (idx >= 12 * hw) return;
    int bf = idx / hw; int r = idx - bf * hw;
    int y = r / wl, x = r - y * wl;
    float fx = flow[((i64)bf * 2) * hw + r];
    float fy = flow[((i64)bf * 2 + 1) * hw + r];
    float sx = x + fx, sy = y + fy;
    float x0f = floorf(sx), y0f = floorf(sy);
    float dx = sx - x0f, dy = sy - y0f;
    int x0 = (int)fminf(fmaxf(x0f, 0.f), (float)(wl - 1));
    int x1 = (int)fminf(fmaxf(x0f + 1.f, 0.f), (float)(wl - 1));
    int y0 = (int)fminf(fmaxf(y0f, 0.f), (float)(hl - 1));
    int y1 = (int)fminf(fmaxf(y0f + 1.f, 0.f), (float)(hl - 1));
    float wa = (1.f - dx) * (1.f - dy), wb = (1.f - dx) * dy, wc = dx * (1.f - dy), wd = dx * dy;
    for (int c = 0; c < 3; ++c) {
        const float* src = b2 + ((i64)bf * 3 + c) * hw;
        float wv = wa * src[y0 * wl + x0] + wb * src[y1 * wl + x0] +
                   wc * src[y0 * wl + x1] + wd * src[y1 * wl + x1];
        inp[((i64)bf * 8 + c) * hw + r] = a[((i64)bf * 3 + c) * hw + r];
        inp[((i64)bf * 8 + 3 + c) * hw + r] = wv;
    }
    inp[((i64)bf * 8 + 6) * hw + r] = fx;
    inp[((i64)bf * 8 + 7) * hw + r] = fy;
}

// out = 2 * jax.image.resize(in, 2x, 'bilinear')  (half-pixel + edge renorm == clamped sample)
__global__ void resize_flow_k(const float* __restrict__ in, float* __restrict__ out, int hi, int wi) {
    int ho = hi * 2, wo = wi * 2;
    int idx = blockIdx.x * blockDim.x + threadIdx.x;
    if (idx >= 12 * 2 * ho * wo) return;
    int x = idx % wo; int y = (idx / wo) % ho; int c = idx / (wo * ho);
    float py = fminf(fmaxf(0.5f * y - 0.25f, 0.f), (float)(hi - 1));
    float px = fminf(fmaxf(0.5f * x - 0.25f, 0.f), (float)(wi - 1));
    int y0 = (int)py; int x0 = (int)px;
    int y1 = min(y0 + 1, hi - 1); int x1 = min(x0 + 1, wi - 1);
    float dy = py - y0, dx = px - x0;
    const float* ip = in + (i64)c * hi * wi;
    float v = (1.f - dy) * ((1.f - dx) * ip[y0 * wi + x0] + dx * ip[y0 * wi + x1]) +
              dy * ((1.f - dx) * ip[y1 * wi + x0] + dx * ip[y1 * wi + x1]);
    out[idx] = 2.f * v;
}

__global__ void copy_slot0_k(const float* __restrict__ f6, float* __restrict__ f5) {
    i64 idx = (i64)blockIdx.x * blockDim.x + threadIdx.x;
    if (idx >= (i64)NB * CH * HW) return;
    int p = (int)(idx & 4095); i64 bc = idx >> 12;
    f5[bc * (i64)TF * HW + p] = f6[idx];
}

// ---------------------------------------------------------------- implicit-warp attention
// 8 pixels per block, 128 threads. Weights pre-transposed: wt[j][o].
__global__ __launch_bounds__(128) void attn_k(
    const float* __restrict__ prop, i64 pbs, i64 pcs,
    const float* __restrict__ cur,
    const float* __restrict__ flows, int fidx,
    const float* __restrict__ wq_t, const float* __restrict__ wq_b,
    const float* __restrict__ wk_t, const float* __restrict__ wk_b,
    const float* __restrict__ wv_t, const float* __restrict__ wv_b,
    const float* __restrict__ wo_t, const float* __restrict__ wo_b,
    float* __restrict__ outp, i64 obs, i64 ocs)
{
    __shared__ float s_q[8][128];      // qin -> q -> o
    __shared__ float s_k[8][4][128];   // g+pe -> k
    __shared__ float s_v[8][4][128];   // g    -> v
    __shared__ float s_att[8][4][8];
    __shared__ float s_dx[8], s_dy[8];
    __shared__ int s_nx[8][2], s_ny[8][2];
    const int tid = threadIdx.x;
    const int b = blockIdx.y;
    const int p0 = blockIdx.x * 8;

    if (tid < 8) {
        int p = p0 + tid;
        int gx = p & 63, gy = p >> 6;
        float fx = flows[((i64)(b * 6 + fidx) * 2) * HW + p];
        float fy = flows[((i64)(b * 6 + fidx) * 2 + 1) * HW + p];
        float sx = gx + fx, sy = gy + fy;
        float fxf = floorf(sx), fyf = floorf(sy);
        s_dx[tid] = sx - fxf; s_dy[tid] = sy - fyf;
        s_nx[tid][0] = (int)fminf(fmaxf(fxf, 0.f), 63.f);
        s_nx[tid][1] = (int)fminf(fmaxf(fxf + 1.f, 0.f), 63.f);
        s_ny[tid][0] = (int)fminf(fmaxf(fyf, 0.f), 63.f);
        s_ny[tid][1] = (int)fminf(fmaxf(fyf + 1.f, 0.f), 63.f);
    }
    __syncthreads();

    const int c = tid;
    const int qd = c >> 5;  // 0:sin(rx) 1:cos(rx) 2:sin(ry) 3:cos(ry)
    const float om = exp2f(-6.643856189774724f * (float)(c & 31) * (1.f / 32.f)); // 0.01^(j/32)

#pragma unroll
    for (int px = 0; px < 8; ++px) {
        int p = p0 + px;
        float dx = s_dx[px], dy = s_dy[px];
        float argq = ((qd < 2) ? dx : dy) * om;
        float peq = (qd & 1) ? __cosf(argq) : __sinf(argq);
        s_q[px][c] = cur[((i64)b * CH + c) * HW + p] + peq;
#pragma unroll
        for (int nb = 0; nb < 4; ++nb) {
            int ox = nb & 1, oy = nb >> 1;
            float g = prop[(i64)b * pbs + (i64)c * pcs + s_ny[px][oy] * 64 + s_nx[px][ox]];
            float rel = (qd < 2) ? ((float)ox - dx) : ((float)oy - dy);
            float arg = rel * om;
            float pe = (qd & 1) ? __cosf(arg) : __sinf(arg);
            s_k[px][nb][c] = g + pe;
            s_v[px][nb][c] = g;
        }
    }
    __syncthreads();

    // q = Wq qin + bq
    {
        float qa[8];
#pragma unroll
        for (int i = 0; i < 8; ++i) qa[i] = 0.f;
        for (int j = 0; j < 128; j += 4) {
            float w0 = wq_t[(j    ) * 128 + tid];
            float w1 = wq_t[(j + 1) * 128 + tid];
            float w2 = wq_t[(j + 2) * 128 + tid];
            float w3 = wq_t[(j + 3) * 128 + tid];
#pragma unroll
            for (int px = 0; px < 8; ++px) {
                const float4 x = *(const float4*)&s_q[px][j];
                qa[px] = fmaf(w0, x.x, fmaf(w1, x.y, fmaf(w2, x.z, fmaf(w3, x.w, qa[px]))));
            }
        }
        __syncthreads();
        float bq = wq_b[tid];
#pragma unroll
        for (int px = 0; px < 8; ++px) s_q[px][tid] = qa[px] + bq;
        __syncthreads();
    }
    // k = Wk (g+pe) + bk
    {
        float ka[8][4];
#pragma unroll
        for (int px = 0; px < 8; ++px)
#pragma unroll
            for (int nb = 0; nb < 4; ++nb) ka[px][nb] = 0.f;
        for (int j = 0; j < 128; j += 4) {
            float w0 = wk_t[(j    ) * 128 + tid];
            float w1 = wk_t[(j + 1) * 128 + tid];
            float w2 = wk_t[(j + 2) * 128 + tid];
            float w3 = wk_t[(j + 3) * 128 + tid];
#pragma unroll
            for (int px = 0; px < 8; ++px)
#pragma unroll
                for (int nb = 0; nb < 4; ++nb) {
                    const float4 x = *(const float4*)&s_k[px][nb][j];
                    ka[px][nb] = fmaf(w0, x.x, fmaf(w1, x.y, fmaf(w2, x.z, fmaf(w3, x.w, ka[px][nb]))));
                }
        }
        __syncthreads();
        float bk = wk_b[tid];
#pragma unroll
        for (int px = 0; px < 8; ++px)
#pragma unroll
            for (int nb = 0; nb < 4; ++nb) s_k[px][nb][tid] = ka[px][nb] + bk;
        __syncthreads();
    }
    // v = Wv g + bv
    {
        float va[8][4];
#pragma unroll
        for (int px = 0; px < 8; ++px)
#pragma unroll
            for (int nb = 0; nb < 4; ++nb) va[px][nb] = 0.f;
        for (int j = 0; j < 128; j += 4) {
            float w0 = wv_t[(j    ) * 128 + tid];
            float w1 = wv_t[(j + 1) * 128 + tid];
            float w2 = wv_t[(j + 2) * 128 + tid];
            float w3 = wv_t[(j + 3) * 128 + tid];
#pragma unroll
            for (int px = 0; px < 8; ++px)
#pragma unroll
                for (int nb = 0; nb < 4; ++nb) {
                    const float4 x = *(const float4*)&s_v[px][nb][j];
                    va[px][nb] = fmaf(w0, x.x, fmaf(w1, x.y, fmaf(w2, x.z, fmaf(w3, x.w, va[px][nb]))));
                }
        }
        __syncthreads();
        float bv = wv_b[tid];
#pragma unroll
        for (int px = 0; px < 8; ++px)
#pragma unroll
            for (int nb = 0; nb < 4; ++nb) s_v[px][nb][tid] = va[px][nb] + bv;
        __syncthreads();
    }
    // logits (scaled by 1/sqrt(16))
#pragma unroll
    for (int it = 0; it < 2; ++it) {
        int item = it * 128 + tid;
        int px = item >> 5, nb = (item >> 3) & 3, h = item & 7;
        const float* qp = &s_q[px][h * 16];
        const float* kp = &s_k[px][nb][h * 16];
        float s = 0.f;
#pragma unroll
        for (int dd = 0; dd < 16; dd += 4) {
            float4 aa = *(const float4*)&qp[dd];
            float4 bb = *(const float4*)&kp[dd];
            s += aa.x * bb.x + aa.y * bb.y + aa.z * bb.z + aa.w * bb.w;
        }
        s_att[px][nb][h] = s * 0.25f;
    }
    __syncthreads();
    if (tid < 64) {
        int px = tid >> 3, h = tid & 7;
        float l0 = s_att[px][0][h], l1 = s_att[px][1][h], l2 = s_att[px][2][h], l3 = s_att[px][3][h];
        float m = fmaxf(fmaxf(l0, l1), fmaxf(l2, l3));
        float e0 = __expf(l0 - m), e1 = __expf(l1 - m), e2 = __expf(l2 - m), e3 = __expf(l3 - m);
        float inv = 1.f / (e0 + e1 + e2 + e3);
        s_att[px][0][h] = e0 * inv; s_att[px][1][h] = e1 * inv;
        s_att[px][2][h] = e2 * inv; s_att[px][3][h] = e3 * inv;
    }
    __syncthreads();
    // o = attn . v
    {
        int h = tid >> 4;
        float ov[8];
#pragma unroll
        for (int px = 0; px < 8; ++px) {
            ov[px] = s_att[px][0][h] * s_v[px][0][tid] + s_att[px][1][h] * s_v[px][1][tid] +
                     s_att[px][2][h] * s_v[px][2][tid] + s_att[px][3][h] * s_v[px][3][tid];
        }
        __syncthreads();
#pragma unroll
        for (int px = 0; px < 8; ++px) s_q[px][tid] = ov[px];
        __syncthreads();
    }
    // out = Wo o + bo
    {
        float oa[8];
#pragma unroll
        for (int i = 0; i < 8; ++i) oa[i] = 0.f;
        for (int j = 0; j < 128; j += 4) {
            float w0 = wo_t[(j    ) * 128 + tid];
            float w1 = wo_t[(j + 1) * 128 + tid];
            float w2 = wo_t[(j + 2) * 128 + tid];
            float w3 = wo_t[(j + 3) * 128 + tid];
#pragma unroll
            for (int px = 0; px < 8; ++px) {
                const float4 x = *(const float4*)&s_q[px][j];
                oa[px] = fmaf(w0, x.x, fmaf(w1, x.y, fmaf(w2, x.z, fmaf(w3, x.w, oa[px]))));
            }
        }
        float bo = wo_b[tid];
#pragma unroll
        for (int px = 0; px < 8; ++px)
            outp[(i64)b * obs + (i64)tid * ocs + (p0 + px)] = oa[px] + bo;
    }
}

// ---------------------------------------------------------------- generic linear: Y[r][o] = act(sum_k X(b,l,k) Wt[k][o] + bias[o])
__global__ void linear_k(
    const float* __restrict__ X, i64 xb, i64 xl, i64 xk, int kmajor,
    const float* __restrict__ Wt, const float* __restrict__ bias,
    float* __restrict__ Y, int Lr, int K, int O, int act)
{
    extern __shared__ float sx[];     // [16][K+4]
    const int tid = threadIdx.x;
    const int r0 = blockIdx.x * 16;
    const int b = r0 / Lr; const int l0 = r0 - b * Lr;
    const int stride = K + 4;
    for (int idx = tid; idx < 16 * K; idx += blockDim.x) {
        int p, k;
        if (kmajor) { k = idx >> 4; p = idx & 15; }
        else { p = idx / K; k = idx - p * K; }
        sx[p * stride + k] = X[(i64)b * xb + (i64)(l0 + p) * xl + (i64)k * xk];
    }
    __syncthreads();
    if (tid < O) {
        float acc[16];
#pragma unroll
        for (int i = 0; i < 16; ++i) acc[i] = 0.f;
        for (int j = 0; j < K; j += 4) {
            float w0 = Wt[(i64)(j    ) * O + tid];
            float w1 = Wt[(i64)(j + 1) * O + tid];
            float w2 = Wt[(i64)(j + 2) * O + tid];
            float w3 = Wt[(i64)(j + 3) * O + tid];
#pragma unroll
            for (int p = 0; p < 16; ++p) {
                const float4 x = *(const float4*)&sx[p * stride + j];
                acc[p] = fmaf(w0, x.x, fmaf(w1, x.y, fmaf(w2, x.z, fmaf(w3, x.w, acc[p]))));
            }
        }
        float bv = bias ? bias[tid] : 0.f;
#pragma unroll
        for (int p = 0; p < 16; ++p) {
            float v = acc[p] + bv;
            if (act == 1) v = fmaxf(v, 0.f) + log1pf(expf(-fabsf(v)));  // softplus
            Y[(i64)(r0 + p) * O + tid] = v;
        }
    }
}

// ---------------------------------------------------------------- mamba causal conv1d + silu
__global__ void conv1d_k(const float* __restrict__ xz, const float* __restrict__ cw,
                         const float* __restrict__ cb, float* __restrict__ xs)
{
    i64 idx = (i64)blockIdx.x * blockDim.x + threadIdx.x;
    if (idx >= (i64)NB * LSEQ * 128) return;
    int d = (int)(idx & 127);
    i64 r = idx >> 7;
    i64 l = r % LSEQ;
    float v = cb[d] + cw[d * 3 + 2] * xz[r * 256 + d];
    if (l >= 1) v += cw[d * 3 + 1] * xz[(r - 1) * 256 + d];
    if (l >= 2) v += cw[d * 3    ] * xz[(r - 2) * 256 + d];
    xs[r * 128 + d] = v / (1.f + expf(-v));
}

// ---------------------------------------------------------------- chunked selective scan
__global__ __launch_bounds__(256) void scan1_k(
    const float* __restrict__ dtb, const float* __restrict__ xsb,
    const float* __restrict__ dbc, const float* __restrict__ Alog,
    float* __restrict__ HEND, float* __restrict__ SDT)
{
    const int tid = threadIdx.x;
    const int pair = blockIdx.x * 16 + (tid >> 4);
    const int s = tid & 15;
    const int b = pair >> 7, d = pair & 127;
    const int ch = blockIdx.y;
    const i64 lbase = (i64)b * LSEQ + (i64)ch * LCHUNK;
    const float a2 = -expf(Alog[d * 16 + s]) * 1.4426950408889634f;
    const float* dtp = dtb + lbase * 128 + d;
    const float* xsp = xsb + lbase * 128 + d;
    const float* Bp  = dbc + lbase * 40 + 8 + s;
    float h = 0.f, sdt = 0.f;
    for (int t = 0; t < LCHUNK; ++t) {
        float dtv = dtp[(i64)t * 128];
        float xsv = xsp[(i64)t * 128];
        float Bv  = Bp[(i64)t * 40];
        h = fmaf(exp2f(dtv * a2), h, dtv * xsv * Bv);
        sdt += dtv;
    }
    HEND[(((i64)b * NCHUNK + ch) * 128 + d) * 16 + s] = h;
    if (s == 0) SDT[((i64)b * NCHUNK + ch) * 128 + d] = sdt;
}

__global__ void scan2_k(const float* __restrict__ HEND, const float* __restrict__ SDT,
                        const float* __restrict__ Alog, float* __restrict__ HSTART)
{
    int idx = blockIdx.x * 256 + threadIdx.x;   // 4096 threads = (b,d,s)
    int b = idx >> 11, d = (idx >> 4) & 127, s = idx & 15;
    float a2 = -expf(Alog[d * 16 + s]) * 1.4426950408889634f;
    float hs = 0.f;
    for (int ch = 0; ch < NCHUNK; ++ch) {
        i64 base = ((i64)b * NCHUNK + ch) * 128 + d;
        HSTART[base * 16 + s] = hs;
        hs = fmaf(exp2f(SDT[base] * a2), hs, HEND[base * 16 + s]);
    }
}

__global__ __launch_bounds__(256) void scan3_k(
    float* __restrict__ dtb,                 // dt in, y out (in-place)
    const float* __restrict__ xsb, const float* __restrict__ dbc,
    const float* __restrict__ Alog, const float* __restrict__ HSTART,
    const float* __restrict__ xz, const float* __restrict__ Dp)
{
    const int tid = threadIdx.x;
    const int pair = blockIdx.x * 16 + (tid >> 4);
    const int s = tid & 15;
    const int b = pair >> 7, d = pair & 127;
    const int ch = blockIdx.y;
    const i64 lbase = (i64)b * LSEQ + (i64)ch * LCHUNK;
    const float a2 = -expf(Alog[d * 16 + s]) * 1.4426950408889634f;
    float* dtp = dtb + lbase * 128 + d;
    const float* xsp = xsb + lbase * 128 + d;
    const float* Bp  = dbc + lbase * 40 + 8 + s;
    const float* Cp  = dbc + lbase * 40 + 24 + s;
    float h = HSTART[(((i64)b * NCHUNK + ch) * 128 + d) * 16 + s];
    const float dp = Dp[d];
    for (int t = 0; t < LCHUNK; ++t) {
        float dtv = dtp[(i64)t * 128];
        float xsv = xsp[(i64)t * 128];
        float Bv  = Bp[(i64)t * 40];
        float Cv  = Cp[(i64)t * 40];
        h = fmaf(exp2f(dtv * a2), h, dtv * xsv * Bv);
        float yc = h * Cv;
        yc += __shfl_xor(yc, 1, 16);
        yc += __shfl_xor(yc, 2, 16);
        yc += __shfl_xor(yc, 4, 16);
        yc += __shfl_xor(yc, 8, 16);
        if (s == 0) {
            float zv = xz[(lbase + t) * 256 + 128 + d];
            float yf = (yc + xsv * dp) * (zv / (1.f + expf(-zv)));
            dtp[(i64)t * 128] = yf;
        }
    }
}

// ---------------------------------------------------------------- fused out-channel-regroup + 1x1 conv + lrelu
// out128[b,o,p] = lrelu( sum_{d,t} w1[o, d*7+t] * mo[b, t*HW+p, d] + b1[o] )
__global__ __launch_bounds__(128) void conv1x1_k(
    const float* __restrict__ mo, const float* __restrict__ w1t,
    const float* __restrict__ b1, float* __restrict__ out128)
{
    __shared__ float sx[4][896];
    const int tid = threadIdx.x;
    const int b = blockIdx.y;
    const int p0 = blockIdx.x * 4;
#pragma unroll
    for (int px = 0; px < 4; ++px) {
        int p = p0 + px;
#pragma unroll
        for (int t = 0; t < 7; ++t)
            sx[px][tid * 7 + t] = mo[((i64)b * LSEQ + t * HW + p) * 128 + tid];
    }
    __syncthreads();
    float acc[4] = {0.f, 0.f, 0.f, 0.f};
    for (int j = 0; j < 896; j += 4) {
        float w0 = w1t[(j    ) * 128 + tid];
        float w1 = w1t[(j + 1) * 128 + tid];
        float w2 = w1t[(j + 2) * 128 + tid];
        float w3 = w1t[(j + 3) * 128 + tid];
#pragma unroll
        for (int px = 0; px < 4; ++px) {
            const float4 x = *(const float4*)&sx[px][j];
            acc[px] = fmaf(w0, x.x, fmaf(w1, x.y, fmaf(w2, x.z, fmaf(w3, x.w, acc[px]))));
        }
    }
    float bv = b1[tid];
#pragma unroll
    for (int px = 0; px < 4; ++px)
        out128[((i64)b * 128 + tid) * HW + (p0 + px)] = lrelu_f(acc[px] + bv);
}

// ================================================================ host
extern "C" void kernel_launch(void* const* d_in, const int* in_sizes, int n_in,
                              void* d_out, int out_size, void* d_ws, size_t ws_size,
                              hipStream_t stream) {
    (void)in_sizes; (void)n_in; (void)out_size; (void)ws_size;
    const float* Lin[7];
    for (int i = 0; i < 7; ++i) Lin[i] = (const float*)d_in[i];
    const float* conv_rec_w = (const float*)d_in[7];
    const float* conv_rec_b = (const float*)d_in[8];
    const float* conv3_w    = (const float*)d_in[9];
    const float* conv3_b    = (const float*)d_in[10];
    const float* conv1x1_w  = (const float*)d_in[11];
    const float* conv1x1_b  = (const float*)d_in[12];
    const float* conv13_w   = (const float*)d_in[13];
    const float* conv13_b   = (const float*)d_in[14];
    const float* wq_w = (const float*)d_in[15]; const float* wq_b = (const float*)d_in[16];
    const float* wk_w = (const float*)d_in[17]; const float* wk_b = (const float*)d_in[18];
    const float* wv_w = (const float*)d_in[19]; const float* wv_b = (const float*)d_in[20];
    const float* wo_w = (const float*)d_in[21]; const float* wo_b = (const float*)d_in[22];
    const float* m_in_w    = (const float*)d_in[23];
    const float* m_conv_w  = (const float*)d_in[24];
    const float* m_conv_b  = (const float*)d_in[25];
    const float* m_xproj_w = (const float*)d_in[26];
    const float* m_dt_w    = (const float*)d_in[27];
    const float* m_dt_b    = (const float*)d_in[28];
    const float* m_Alog    = (const float*)d_in[29];
    const float* m_D       = (const float*)d_in[30];
    const float* m_out_w   = (const float*)d_in[31];
    const float* spy1_w = (const float*)d_in[32]; const float* spy1_b = (const float*)d_in[33];
    const float* spy2_w = (const float*)d_in[34]; const float* spy2_b = (const float*)d_in[35];
    float* out = (float*)d_out;
    float* W = (float*)d_ws;

    // -------- workspace layout (floats); total ~51.36M floats (~196 MiB)
    i64 off = 0;
    float* FEATS  = W + off; off += (i64)TF * NB * CH * HW;       // 7x(2,128,64,64)
    float* FEATS5 = W + off; off += (i64)NB * CH * TF * HW;       // (2,128,7,4096)
    float* XZ     = W + off; off += (i64)NB * LSEQ * 256;         // in-proj out; later out-proj out (MO)
    float* XS     = W + off; off += (i64)NB * LSEQ * 128;         // conv1d+silu
    float* DBC    = W + off; off += (i64)NB * LSEQ * 40;
    float* DT     = W + off; off += (i64)NB * LSEQ * 128;         // dt; later y (in-place)
    float* OUT128 = W + off; off += (i64)NB * 128 * HW;
    float* WQ_T = W + off; off += 16384;
    float* WK_T = W + off; off += 16384;
    float* WV_T = W + off; off += 16384;
    float* WO_T = W + off; off += 16384;
    float* MIN_T  = W + off; off += 256 * 128;
    float* MXP_T  = W + off; off += 40 * 128;
    float* MDT_T  = W + off; off += 128 * 8;
    float* MOUT_T = W + off; off += 16384;
    float* W1_T   = W + off; off += 128 * 896;
    float* LQS  = W + off; off += (i64)NB * TF * 3 * HW;
    float* P1_0 = W + off; off += 12 * 3 * HW;
    float* P2_0 = W + off; off += 12 * 3 * HW;
    float* P1_1 = W + off; off += 12 * 3 * 1024;
    float* P2_1 = W + off; off += 12 * 3 * 1024;
    float* P1_2 = W + off; off += 12 * 3 * 256;
    float* P2_2 = W + off; off += 12 * 3 * 256;
    float* FLOW2 = W + off; off += 12 * 2 * 256;
    float* FLOW1 = W + off; off += 12 * 2 * 1024;
    float* FLOW0 = W + off; off += 12 * 2 * HW;                   // final flows (b*6+i,2,HW)
    float* INP = W + off; off += 12 * 8 * HW;
    float* HHB = W + off; off += 12 * 32 * HW;
    float* HEND   = W + off; off += (i64)NB * NCHUNK * 128 * 16;
    float* HSTART = W + off; off += (i64)NB * NCHUNK * 128 * 16;
    float* SDT    = W + off; off += (i64)NB * NCHUNK * 128;
    float* MO = XZ;  // out-proj output aliases xz (z fully consumed by then)

    // -------- weight transposes
    auto T = [&](const float* src, float* dst, int R, int Cc) {
        transpose_k<<<cdiv((i64)R * Cc, 256), 256, 0, stream>>>(src, dst, R, Cc);
    };
    T(wq_w, WQ_T, 128, 128); T(wk_w, WK_T, 128, 128);
    T(wv_w, WV_T, 128, 128); T(wo_w, WO_T, 128, 128);
    T(m_in_w, MIN_T, 256, 128); T(m_xproj_w, MXP_T, 40, 128);
    T(m_dt_w, MDT_T, 128, 8);   T(m_out_w, MOUT_T, 128, 128);
    T(conv1x1_w, W1_T, 128, 896);

    // -------- conv_rec (lqs) and conv3+lrelu (feats)
    for (int t = 0; t < 7; ++t) {
        conv3x3_k<<<dim3(16, 1, 2), 256, 0, stream>>>(
            Lin[t], 128, (i64)128 * HW, nullptr, 0, 0,
            conv_rec_w, conv_rec_b, 3, 64, 64, nullptr, 0,
            LQS + (i64)t * 3 * HW, (i64)21 * HW, 0);
        conv3x3_k<<<dim3(16, 8, 2), 256, 0, stream>>>(
            Lin[t], 128, (i64)128 * HW, nullptr, 0, 0,
            conv3_w, conv3_b, 128, 64, 64, nullptr, 0,
            FEATS + (i64)t * NB * CH * HW, (i64)CH * HW, 1);
    }

    // -------- spynet
    copy_pyr_k<<<cdiv(12 * 3 * HW, 256), 256, 0, stream>>>(LQS, P1_0, 0);
    copy_pyr_k<<<cdiv(12 * 3 * HW, 256), 256, 0, stream>>>(LQS, P2_0, 1);
    avgpool_k<<<cdiv(36 * 32 * 32, 256), 256, 0, stream>>>(P1_0, P1_1, 36, 64, 64);
    avgpool_k<<<cdiv(36 * 32 * 32, 256), 256, 0, stream>>>(P2_0, P2_1, 36, 64, 64);
    avgpool_k<<<cdiv(36 * 16 * 16, 256), 256, 0, stream>>>(P1_1, P1_2, 36, 32, 32);
    avgpool_k<<<cdiv(36 * 16 * 16, 256), 256, 0, stream>>>(P2_1, P2_2, 36, 32, 32);
    hipMemsetAsync(FLOW2, 0, 12 * 2 * 256 * sizeof(float), stream);

    struct Lvl { float *p1, *p2, *fl; int hw_; };
    Lvl lv[3] = { {P1_2, P2_2, FLOW2, 16}, {P1_1, P2_1, FLOW1, 32}, {P1_0, P2_0, FLOW0, 64} };
    for (int li = 0; li < 3; ++li) {
        int hl = lv[li].hw_;
        int hw = hl * hl;
        int tiles = (hl / 16) * (hl / 16);
        build_inp_k<<<cdiv(12 * hw, 256), 256, 0, stream>>>(lv[li].p1, lv[li].p2, lv[li].fl, INP, hl, hl);
        conv3x3_k<<<dim3(tiles, 2, 12), 256, 0, stream>>>(
            INP, 8, (i64)8 * hw, nullptr, 0, 0, spy1_w, spy1_b, 32, hl, hl,
            nullptr, 0, HHB, (i64)32 * hw, 1);
        conv3x3_k<<<dim3(tiles, 1, 12), 256, 0, stream>>>(
            HHB, 32, (i64)32 * hw, nullptr, 0, 0, spy2_w, spy2_b, 2, hl, hl,
            lv[li].fl, (i64)2 * hw, lv[li].fl, (i64)2 * hw, 0);
        if (li < 2) {
            int ho = hl * 2;
            resize_flow_k<<<cdiv(12 * 2 * ho * ho, 256), 256, 0, stream>>>(lv[li].fl, lv[li + 1].fl, hl, hl);
        }
    }

    // -------- propagation: feats5[:, :, 0] = feats[6]; slots 1..6 = implicit_warp outputs
    copy_slot0_k<<<cdiv((i64)NB * CH * HW, 256), 256, 0, stream>>>(FEATS + 6LL * NB * CH * HW, FEATS5);
    for (int i = 1; i <= 6; ++i) {
        int fidx = 6 - i;
        const float* cur = FEATS + (i64)fidx * NB * CH * HW;
        const float* prop; i64 pbs, pcs;
        if (i == 1) { prop = FEATS + 6LL * NB * CH * HW; pbs = (i64)CH * HW; pcs = HW; }
        else { prop = FEATS5 + (i64)(i - 1) * HW; pbs = (i64)CH * TF * HW; pcs = (i64)TF * HW; }
        attn_k<<<dim3(512, 2), 128, 0, stream>>>(
            prop, pbs, pcs, cur, FLOW0, fidx,
            WQ_T, wq_b, WK_T, wk_b, WV_T, wv_b, WO_T, wo_b,
            FEATS5 + (i64)i * HW, (i64)CH * TF * HW, (i64)TF * HW);
    }

    // -------- mamba
    const int nrow_blocks = (NB * LSEQ) / 16;   // 3584
    // in-proj: x[b,l,c] = feats5[(b*128+c)*LSEQ + l]
    linear_k<<<nrow_blocks, 256, 16 * (128 + 4) * 4, stream>>>(
        FEATS5, (i64)CH * LSEQ, 1, LSEQ, 1, MIN_T, nullptr, XZ, LSEQ, 128, 256, 0);
    conv1d_k<<<cdiv((i64)NB * LSEQ * 128, 256), 256, 0, stream>>>(XZ, m_conv_w, m_conv_b, XS);
    linear_k<<<nrow_blocks, 64, 16 * (128 + 4) * 4, stream>>>(
        XS, (i64)LSEQ * 128, 128, 1, 0, MXP_T, nullptr, DBC, LSEQ, 128, 40, 0);
    linear_k<<<nrow_blocks, 128, 16 * (8 + 4) * 4, stream>>>(
        DBC, (i64)LSEQ * 40, 40, 1, 0, MDT_T, m_dt_b, DT, LSEQ, 8, 128, 1);
    scan1_k<<<dim3(16, NCHUNK), 256, 0, stream>>>(DT, XS, DBC, m_Alog, HEND, SDT);
    scan2_k<<<16, 256, 0, stream>>>(HEND, SDT, m_Alog, HSTART);
    scan3_k<<<dim3(16, NCHUNK), 256, 0, stream>>>(DT, XS, DBC, m_Alog, HSTART, XZ, m_D);
    // out-proj: y(=DT) @ m_out_w.T -> MO (aliases XZ)
    linear_k<<<nrow_blocks, 128, 16 * (128 + 4) * 4, stream>>>(
        DT, (i64)LSEQ * 128, 128, 1, 0, MOUT_T, nullptr, MO, LSEQ, 128, 128, 0);
    // channel regroup (d,t) -> 896, 1x1 conv, lrelu
    conv1x1_k<<<dim3(1024, 2), 128, 0, stream>>>(MO, W1_T, conv1x1_b, OUT128);

    // -------- final conv13 + lrelu + residual, straight into d_out
    for (int t = 0; t < 7; ++t) {
        conv3x3_k<<<dim3(16, 8, 2), 256, 0, stream>>>(
            FEATS + (i64)t * NB * CH * HW, 128, (i64)CH * HW,
            OUT128, 128, (i64)128 * HW,
            conv13_w, conv13_b, 128, 64, 64,
            Lin[t], (i64)CH * HW,
            out + (i64)t * NB * CH * HW, (i64)CH * HW, 1);
    }
}

// Round 2
// 1616.346 us; speedup vs baseline: 3.2094x; 3.2094x over previous
//
#include <hip/hip_runtime.h>
#include <hip/hip_bf16.h>
#include <math.h>

// Problem constants
#define NB   2        // batch N
#define CH   128      // C
#define HT   64
#define WD   64
#define HW   4096     // H*W
#define TF   7        // frames
#define LSEQ 28672    // 7*4096
#define NCHUNK 128    // mamba scan chunks (per batch)
#define LCHUNK 224    // 128*224 = 28672

typedef long long i64;
typedef float f32x4 __attribute__((ext_vector_type(4)));
typedef short sv8 __attribute__((ext_vector_type(8)));
typedef short sv4 __attribute__((ext_vector_type(4)));

struct Ptr7 { const float* p[7]; };

static inline int cdiv(i64 a, int b) { return (int)((a + b - 1) / b); }

__device__ __forceinline__ float lrelu_f(float v) { return v >= 0.f ? v : 0.1f * v; }

__device__ __forceinline__ short bf16r(float f) {
    unsigned u = __float_as_uint(f);
    unsigned r = (u + 0x7FFFu + ((u >> 16) & 1u)) >> 16;
    return (short)r;
}

// ---------------------------------------------------------------- transpose (weights)
__global__ void transpose_k(const float* __restrict__ src, float* __restrict__ dst, int R, int Cc) {
    i64 idx = (i64)blockIdx.x * blockDim.x + threadIdx.x;
    if (idx >= (i64)R * Cc) return;
    int r = (int)(idx / Cc), c = (int)(idx - (i64)r * Cc);
    dst[(i64)c * R + r] = src[idx];
}

// ---------------------------------------------------------------- weight prep for MFMA conv
// wb[k9][cc][co][cgp][e] = bf16( w[co][ci = cc*64 + (cgp^(co&7))*8 + e][ky][kx] ), k9=ky*3+kx
__global__ void wprep_k(const float* __restrict__ w, short* __restrict__ wb, int CinT, int CC) {
    int idx = blockIdx.x * 256 + threadIdx.x;
    int total = 9 * CC * 8192;
    if (idx >= total) return;
    int e   = idx & 7;
    int cgp = (idx >> 3) & 7;
    int co  = (idx >> 6) & 127;
    int rest = idx >> 13;            // k9*CC + cc
    int cc = rest % CC, k9 = rest / CC;
    int cg = cgp ^ (co & 7);
    int ci = cc * 64 + cg * 8 + e;
    wb[idx] = bf16r(w[((i64)co * CinT + ci) * 9 + k9]);
}

// ---------------------------------------------------------------- input transpose: Lin fp32 [b][ci][p] -> TIN bf16 [z][p][ci]
__global__ __launch_bounds__(256) void tprep_k(Ptr7 lin, short* __restrict__ tin) {
    __shared__ short st[128 * 130];
    const int tid = threadIdx.x;
    const int pg = blockIdx.x;       // 32 groups of 128 px
    const int z = blockIdx.y; const int t = z >> 1, b = z & 1;
    const float* src = lin.p[t] + (i64)b * 128 * HW + pg * 128;
    int p_ = tid & 127, cihalf = tid >> 7;
    for (int ci0 = 0; ci0 < 128; ci0 += 2) {
        int ci = ci0 + cihalf;
        st[p_ * 130 + ci] = bf16r(src[(i64)ci * HW + p_]);
    }
    __syncthreads();
    for (int it = 0; it < 32; ++it) {
        int o = it * 256 + tid;              // 8192 int units
        int p = o >> 6, cp = o & 63;
        *(int*)&tin[((i64)z * HW + pg * 128 + p) * 128 + cp * 2] = *(int*)&st[p * 130 + cp * 2];
    }
}

// ---------------------------------------------------------------- MFMA 3x3 conv (pad=1), implicit GEMM
// A = weights (M=co 128), B = pixels (N=128: 2 rows of 64), K = CC*64*9
__global__ __launch_bounds__(256) void convmfma_k(
    const short* __restrict__ srcA, const short* __restrict__ srcB, int CC, int chA,
    const short* __restrict__ WB, const float* __restrict__ bias,
    Ptr7 res, int has_res,
    float* __restrict__ outf, short* __restrict__ outb, int relu)
{
    __shared__ short SA[264 * 64];   // [pos][cg'*8], cg' = cg ^ (pos&7)
    __shared__ short SB[128 * 64];   // [co][cg'*8],  cg' = cg ^ (co&7)
    const int tid = threadIdx.x;
    const int rp = blockIdx.x;       // rowpair 0..31
    const int z = blockIdx.y;        // 0..13
    const int t = z >> 1, b = z & 1;
    const int y0 = rp * 2;
    const int pbase = rp * 128;
    const int lane = tid & 63, wv = tid >> 6;
    const int wm = wv & 1, wn = wv >> 1;
    const int l15 = lane & 15, l4 = lane >> 4;

    f32x4 acc[4][4];
    f32x4 zz = {0.f, 0.f, 0.f, 0.f};
#pragma unroll
    for (int i = 0; i < 4; ++i)
#pragma unroll
        for (int j = 0; j < 4; ++j) acc[i][j] = zz;

    for (int cc = 0; cc < CC; ++cc) {
        __syncthreads();
        {   // ---- stage A tile: 4 rows (y0-1..y0+2) x 66 cols x 64 ci
            const short* sp = (cc < chA) ? srcA + (i64)z * HW * 128 + cc * 64
                                         : srcB + (i64)b * HW * 128 + (cc - chA) * 64;
            int cg = tid & 7;
            for (int it = 0; it < 9; ++it) {
                int pos = it * 32 + (tid >> 3);
                if (pos < 264) {
                    int r = pos / 66, ccol = pos - r * 66;
                    int gy = y0 - 1 + r, gx = ccol - 1;
                    int4 val = {0, 0, 0, 0};
                    if (gy >= 0 && gy < 64 && gx >= 0 && gx < 64)
                        val = *(const int4*)(sp + ((i64)(gy * 64 + gx)) * 128 + cg * 8);
                    *(int4*)&SA[pos * 64 + ((cg ^ (pos & 7)) * 8)] = val;
                }
            }
        }
        for (int k9 = 0; k9 < 9; ++k9) {
            __syncthreads();
            {   // ---- stage B: 16 KB linear copy (fragment-order prepped)
                const short* wsrc = WB + ((i64)(k9 * CC + cc)) * 8192;
                for (int it = 0; it < 4; ++it) {
                    int o = it * 256 + tid;
                    *(int4*)&SB[o * 8] = *(const int4*)(wsrc + o * 8);
                }
            }
            __syncthreads();
            const int ky = k9 / 3, kx = k9 - ky * 3;
#pragma unroll
            for (int ks = 0; ks < 2; ++ks) {
                sv8 af[4], bf_[4];
                int cgk = ks * 4 + l4;
#pragma unroll
                for (int mt = 0; mt < 4; ++mt) {
                    int co = wm * 64 + mt * 16 + l15;
                    af[mt] = *(const sv8*)&SB[co * 64 + ((cgk ^ (co & 7)) * 8)];
                }
#pragma unroll
                for (int nt = 0; nt < 4; ++nt) {
                    int pos = (wn + ky) * 66 + nt * 16 + l15 + kx;
                    bf_[nt] = *(const sv8*)&SA[pos * 64 + ((cgk ^ (pos & 7)) * 8)];
                }
#pragma unroll
                for (int mt = 0; mt < 4; ++mt)
#pragma unroll
                    for (int nt = 0; nt < 4; ++nt)
                        acc[mt][nt] = __builtin_amdgcn_mfma_f32_16x16x32_bf16(af[mt], bf_[nt], acc[mt][nt], 0, 0, 0);
            }
        }
    }
    // ---- epilogue: D[co][pix]; lane: co = base + l4*4 + r, pix = base + l15
    const float* rptr = has_res ? (res.p[t] + (i64)b * 128 * HW) : nullptr;
#pragma unroll
    for (int mt = 0; mt < 4; ++mt) {
        int co0 = wm * 64 + mt * 16 + l4 * 4;
#pragma unroll
        for (int nt = 0; nt < 4; ++nt) {
            int pix = pbase + wn * 64 + nt * 16 + l15;
            float vv[4];
#pragma unroll
            for (int r = 0; r < 4; ++r) {
                float x = acc[mt][nt][r] + bias[co0 + r];
                if (relu) x = lrelu_f(x);
                if (rptr) x += rptr[(i64)(co0 + r) * HW + pix];
                outf[((i64)z * 128 + co0 + r) * HW + pix] = x;
                vv[r] = x;
            }
            if (outb) {
                sv4 pk;
#pragma unroll
                for (int r = 0; r < 4; ++r) pk[r] = bf16r(vv[r]);
                *(sv4*)&outb[((i64)z * HW + pix) * 128 + co0] = pk;
            }
        }
    }
}

// ---------------------------------------------------------------- conv_rec (128->3) fp32, all frames in one launch
__global__ __launch_bounds__(256) void convrec_k(Ptr7 lin, const float* __restrict__ w,
                                                 const float* __restrict__ bias, float* __restrict__ lqs) {
    __shared__ float s_in[16][18][18];
    __shared__ float s_w[3][16][9];
    const int tid = threadIdx.x;
    const int tx = tid & 15, ty = tid >> 4;
    const int tile = blockIdx.x;
    const int z = blockIdx.y; const int t = z >> 1, b = z & 1;
    const int tx0 = (tile & 3) << 4, ty0 = (tile >> 2) << 4;
    const float* in = lin.p[t] + (i64)b * 128 * HW;
    float acc[3] = {bias[0], bias[1], bias[2]};
    for (int ci0 = 0; ci0 < 128; ci0 += 16) {
        for (int idx = tid; idx < 16 * 324; idx += 256) {
            int chn = idx / 324; int r = idx - chn * 324;
            int iy = r / 18; int ix = r - iy * 18;
            int gy = ty0 + iy - 1, gx = tx0 + ix - 1;
            float v = 0.f;
            if (gy >= 0 && gy < 64 && gx >= 0 && gx < 64)
                v = in[(i64)(ci0 + chn) * HW + gy * 64 + gx];
            s_in[chn][iy][ix] = v;
        }
        for (int idx = tid; idx < 3 * 16 * 9; idx += 256) {
            int co = idx / 144; int r = idx - co * 144;
            int ci = r / 9; int k = r - ci * 9;
            s_w[co][ci][k] = w[((i64)co * 128 + ci0 + ci) * 9 + k];
        }
        __syncthreads();
#pragma unroll 4
        for (int ci = 0; ci < 16; ++ci) {
#pragma unroll
            for (int ky = 0; ky < 3; ++ky)
#pragma unroll
                for (int kx = 0; kx < 3; ++kx) {
                    float xv = s_in[ci][ty + ky][tx + kx];
#pragma unroll
                    for (int co = 0; co < 3; ++co)
                        acc[co] = fmaf(s_w[co][ci][ky * 3 + kx], xv, acc[co]);
                }
        }
        __syncthreads();
    }
    int p = (ty0 + ty) * 64 + tx0 + tx;
#pragma unroll
    for (int co = 0; co < 3; ++co)
        lqs[(i64)b * 21 * HW + (i64)t * 3 * HW + (i64)co * HW + p] = acc[co];
}

// ---------------------------------------------------------------- generic fp32 3x3 conv (spynet only now)
__global__ __launch_bounds__(256) void conv3x3_k(
    const float* __restrict__ in1, int Cin1, i64 in1_bs,
    const float* __restrict__ in2, int Cin2, i64 in2_bs,
    const float* __restrict__ w, const float* __restrict__ bias, int Cout,
    int H, int W,
    const float* __restrict__ res, i64 res_bs,
    float* __restrict__ out, i64 out_bs, int relu)
{
    __shared__ float s_in[16][18][18];
    __shared__ float s_w[16][9][16];   // [ci][k][co]
    const int tid = threadIdx.x;
    const int tx = tid & 15, ty = tid >> 4;
    const int tX = W >> 4;
    const int tx0 = (blockIdx.x % tX) << 4, ty0 = (blockIdx.x / tX) << 4;
    const int co0 = blockIdx.y << 4;
    const int z = blockIdx.z;
    const int CinT = Cin1 + Cin2;
    const i64 hw = (i64)H * W;

    float acc[16];
#pragma unroll
    for (int i = 0; i < 16; ++i) acc[i] = 0.f;

    for (int ci0 = 0; ci0 < CinT; ci0 += 16) {
        for (int idx = tid; idx < 16 * 324; idx += 256) {
            int chn = idx / 324; int r = idx - chn * 324;
            int iy = r / 18; int ix = r - iy * 18;
            int gy = ty0 + iy - 1, gx = tx0 + ix - 1;
            int ci = ci0 + chn;
            float v = 0.f;
            if (ci < CinT && gy >= 0 && gy < H && gx >= 0 && gx < W) {
                if (ci < Cin1) v = in1[(i64)z * in1_bs + (i64)ci * hw + gy * W + gx];
                else           v = in2[(i64)z * in2_bs + (i64)(ci - Cin1) * hw + gy * W + gx];
            }
            s_in[chn][iy][ix] = v;
        }
        for (int idx = tid; idx < 16 * 144; idx += 256) {
            int co = idx / 144; int r = idx - co * 144;
            int ci = r / 9; int k = r - ci * 9;
            float v = 0.f;
            int gco = co0 + co, gci = ci0 + ci;
            if (gco < Cout && gci < CinT) v = w[((i64)gco * CinT + gci) * 9 + k];
            s_w[ci][k][co] = v;
        }
        __syncthreads();
#pragma unroll 2
        for (int ci = 0; ci < 16; ++ci) {
#pragma unroll
            for (int ky = 0; ky < 3; ++ky) {
#pragma unroll
                for (int kx = 0; kx < 3; ++kx) {
                    float xv = s_in[ci][ty + ky][tx + kx];
                    const float4* wr = (const float4*)(&s_w[ci][ky * 3 + kx][0]);
                    float wv[16];
                    ((float4*)wv)[0] = wr[0];
                    ((float4*)wv)[1] = wr[1];
                    ((float4*)wv)[2] = wr[2];
                    ((float4*)wv)[3] = wr[3];
#pragma unroll
                    for (int co = 0; co < 16; ++co) acc[co] = fmaf(wv[co], xv, acc[co]);
                }
            }
        }
        __syncthreads();
    }
    int y = ty0 + ty, x = tx0 + tx;
#pragma unroll
    for (int co = 0; co < 16; ++co) {
        int gco = co0 + co;
        if (gco < Cout) {
            float v = acc[co] + bias[gco];
            if (relu) v = lrelu_f(v);
            if (res) v += res[(i64)z * res_bs + (i64)gco * hw + y * W + x];
            out[(i64)z * out_bs + (i64)gco * hw + y * W + x] = v;
        }
    }
}

// ---------------------------------------------------------------- spynet helpers
__global__ void copy_pyr_k(const float* __restrict__ lqs, float* __restrict__ dst, int shift) {
    int idx = blockIdx.x * blockDim.x + threadIdx.x;
    if (idx >= 12 * 3 * HW) return;
    int p = idx & 4095; int rest = idx >> 12; int c = rest % 3; int bf = rest / 3;
    int b = bf / 6, i = bf % 6;
    dst[idx] = lqs[(((i64)b * 7 + i + shift) * 3 + c) * HW + p];
}

__global__ void avgpool_k(const float* __restrict__ in, float* __restrict__ out, int nc, int hi, int wi) {
    int ho = hi >> 1, wo = wi >> 1;
    int idx = blockIdx.x * blockDim.x + threadIdx.x;
    if (idx >= nc * ho * wo) return;
    int x = idx % wo; int y = (idx / wo) % ho; int c = idx / (wo * ho);
    const float* ip = in + (i64)c * hi * wi;
    out[idx] = 0.25f * (ip[(2 * y) * wi + 2 * x] + ip[(2 * y) * wi + 2 * x + 1] +
                        ip[(2 * y + 1) * wi + 2 * x] + ip[(2 * y + 1) * wi + 2 * x + 1]);
}

__global__ void build_inp_k(const float* __restrict__ a, const float* __restrict__ b2,
                            const float* __restrict__ flow, float* __restrict__ inp, int hl, int wl) {
    int idx = blockIdx.x * blockDim.x + threadIdx.x;
    int hw = hl * wl;
    if (idx >= 12 * hw) return;
    int bf = idx / hw; int r = idx - bf * hw;
    int y = r / wl, x = r - y * wl;
    float fx = flow[((i64)bf * 2) * hw + r];
    float fy = flow[((i64)bf * 2 + 1) * hw + r];
    float sx = x + fx, sy = y + fy;
    float x0f = floorf(sx), y0f = floorf(sy);
    float dx = sx - x0f, dy = sy - y0f;
    int x0 = (int)fminf(fmaxf(x0f, 0.f), (float)(wl - 1));
    int x1 = (int)fminf(fmaxf(x0f + 1.f, 0.f), (float)(wl - 1));
    int y0 = (int)fminf(fmaxf(y0f, 0.f), (float)(hl - 1));
    int y1 = (int)fminf(fmaxf(y0f + 1.f, 0.f), (float)(hl - 1));
    float wa = (1.f - dx) * (1.f - dy), wb = (1.f - dx) * dy, wc = dx * (1.f - dy), wd = dx * dy;
    for (int c = 0; c < 3; ++c) {
        const float* src = b2 + ((i64)bf * 3 + c) * hw;
        float wv = wa * src[y0 * wl + x0] + wb * src[y1 * wl + x0] +
                   wc * src[y0 * wl + x1] + wd * src[y1 * wl + x1];
        inp[((i64)bf * 8 + c) * hw + r] = a[((i64)bf * 3 + c) * hw + r];
        inp[((i64)bf * 8 + 3 + c) * hw + r] = wv;
    }
    inp[((i64)bf * 8 + 6) * hw + r] = fx;
    inp[((i64)bf * 8 + 7) * hw + r] = fy;
}

__global__ void resize_flow_k(const float* __restrict__ in, float* __restrict__ out, int hi, int wi) {
    int ho = hi * 2, wo = wi * 2;
    int idx = blockIdx.x * blockDim.x + threadIdx.x;
    if (idx >= 12 * 2 * ho * wo) return;
    int x = idx % wo; int y = (idx / wo) % ho; int c = idx / (wo * ho);
    float py = fminf(fmaxf(0.5f * y - 0.25f, 0.f), (float)(hi - 1));
    float px = fminf(fmaxf(0.5f * x - 0.25f, 0.f), (float)(wi - 1));
    int y0 = (int)py; int x0 = (int)px;
    int y1 = min(y0 + 1, hi - 1); int x1 = min(x0 + 1, wi - 1);
    float dy = py - y0, dx = px - x0;
    const float* ip = in + (i64)c * hi * wi;
    float v = (1.f - dy) * ((1.f - dx) * ip[y0 * wi + x0] + dx * ip[y0 * wi + x1]) +
              dy * ((1.f - dx) * ip[y1 * wi + x0] + dx * ip[y1 * wi + x1]);
    out[idx] = 2.f * v;
}

__global__ void copy_slot0_k(const float* __restrict__ f6, float* __restrict__ f5) {
    i64 idx = (i64)blockIdx.x * blockDim.x + threadIdx.x;
    if (idx >= (i64)NB * CH * HW) return;
    int p = (int)(idx & 4095); i64 bc = idx >> 12;
    f5[bc * (i64)TF * HW + p] = f6[idx];
}

// ---------------------------------------------------------------- implicit-warp attention
__global__ __launch_bounds__(128) void attn_k(
    const float* __restrict__ prop, i64 pbs, i64 pcs,
    const float* __restrict__ cur,
    const float* __restrict__ flows, int fidx,
    const float* __restrict__ wq_t, const float* __restrict__ wq_b,
    const float* __restrict__ wk_t, const float* __restrict__ wk_b,
    const float* __restrict__ wv_t, const float* __restrict__ wv_b,
    const float* __restrict__ wo_t, const float* __restrict__ wo_b,
    float* __restrict__ outp, i64 obs, i64 ocs)
{
    __shared__ float s_q[8][128];
    __shared__ float s_k[8][4][128];
    __shared__ float s_v[8][4][128];
    __shared__ float s_att[8][4][8];
    __shared__ float s_dx[8], s_dy[8];
    __shared__ int s_nx[8][2], s_ny[8][2];
    const int tid = threadIdx.x;
    const int b = blockIdx.y;
    const int p0 = blockIdx.x * 8;

    if (tid < 8) {
        int p = p0 + tid;
        int gx = p & 63, gy = p >> 6;
        float fx = flows[((i64)(b * 6 + fidx) * 2) * HW + p];
        float fy = flows[((i64)(b * 6 + fidx) * 2 + 1) * HW + p];
        float sx = gx + fx, sy = gy + fy;
        float fxf = floorf(sx), fyf = floorf(sy);
        s_dx[tid] = sx - fxf; s_dy[tid] = sy - fyf;
        s_nx[tid][0] = (int)fminf(fmaxf(fxf, 0.f), 63.f);
        s_nx[tid][1] = (int)fminf(fmaxf(fxf + 1.f, 0.f), 63.f);
        s_ny[tid][0] = (int)fminf(fmaxf(fyf, 0.f), 63.f);
        s_ny[tid][1] = (int)fminf(fmaxf(fyf + 1.f, 0.f), 63.f);
    }
    __syncthreads();

    const int c = tid;
    const int qd = c >> 5;
    const float om = exp2f(-6.643856189774724f * (float)(c & 31) * (1.f / 32.f));

#pragma unroll
    for (int px = 0; px < 8; ++px) {
        int p = p0 + px;
        float dx = s_dx[px], dy = s_dy[px];
        float argq = ((qd < 2) ? dx : dy) * om;
        float peq = (qd & 1) ? __cosf(argq) : __sinf(argq);
        s_q[px][c] = cur[((i64)b * CH + c) * HW + p] + peq;
#pragma unroll
        for (int nb = 0; nb < 4; ++nb) {
            int ox = nb & 1, oy = nb >> 1;
            float g = prop[(i64)b * pbs + (i64)c * pcs + s_ny[px][oy] * 64 + s_nx[px][ox]];
            float rel = (qd < 2) ? ((float)ox - dx) : ((float)oy - dy);
            float arg = rel * om;
            float pe = (qd & 1) ? __cosf(arg) : __sinf(arg);
            s_k[px][nb][c] = g + pe;
            s_v[px][nb][c] = g;
        }
    }
    __syncthreads();

    {
        float qa[8];
#pragma unroll
        for (int i = 0; i < 8; ++i) qa[i] = 0.f;
        for (int j = 0; j < 128; j += 4) {
            float w0 = wq_t[(j    ) * 128 + tid];
            float w1 = wq_t[(j + 1) * 128 + tid];
            float w2 = wq_t[(j + 2) * 128 + tid];
            float w3 = wq_t[(j + 3) * 128 + tid];
#pragma unroll
            for (int px = 0; px < 8; ++px) {
                const float4 x = *(const float4*)&s_q[px][j];
                qa[px] = fmaf(w0, x.x, fmaf(w1, x.y, fmaf(w2, x.z, fmaf(w3, x.w, qa[px]))));
            }
        }
        __syncthreads();
        float bq = wq_b[tid];
#pragma unroll
        for (int px = 0; px < 8; ++px) s_q[px][tid] = qa[px] + bq;
        __syncthreads();
    }
    {
        float ka[8][4];
#pragma unroll
        for (int px = 0; px < 8; ++px)
#pragma unroll
            for (int nb = 0; nb < 4; ++nb) ka[px][nb] = 0.f;
        for (int j = 0; j < 128; j += 4) {
            float w0 = wk_t[(j    ) * 128 + tid];
            float w1 = wk_t[(j + 1) * 128 + tid];
            float w2 = wk_t[(j + 2) * 128 + tid];
            float w3 = wk_t[(j + 3) * 128 + tid];
#pragma unroll
            for (int px = 0; px < 8; ++px)
#pragma unroll
                for (int nb = 0; nb < 4; ++nb) {
                    const float4 x = *(const float4*)&s_k[px][nb][j];
                    ka[px][nb] = fmaf(w0, x.x, fmaf(w1, x.y, fmaf(w2, x.z, fmaf(w3, x.w, ka[px][nb]))));
                }
        }
        __syncthreads();
        float bk = wk_b[tid];
#pragma unroll
        for (int px = 0; px < 8; ++px)
#pragma unroll
            for (int nb = 0; nb < 4; ++nb) s_k[px][nb][tid] = ka[px][nb] + bk;
        __syncthreads();
    }
    {
        float va[8][4];
#pragma unroll
        for (int px = 0; px < 8; ++px)
#pragma unroll
            for (int nb = 0; nb < 4; ++nb) va[px][nb] = 0.f;
        for (int j = 0; j < 128; j += 4) {
            float w0 = wv_t[(j    ) * 128 + tid];
            float w1 = wv_t[(j + 1) * 128 + tid];
            float w2 = wv_t[(j + 2) * 128 + tid];
            float w3 = wv_t[(j + 3) * 128 + tid];
#pragma unroll
            for (int px = 0; px < 8; ++px)
#pragma unroll
                for (int nb = 0; nb < 4; ++nb) {
                    const float4 x = *(const float4*)&s_v[px][nb][j];
                    va[px][nb] = fmaf(w0, x.x, fmaf(w1, x.y, fmaf(w2, x.z, fmaf(w3, x.w, va[px][nb]))));
                }
        }
        __syncthreads();
        float bv = wv_b[tid];
#pragma unroll
        for (int px = 0; px < 8; ++px)
#pragma unroll
            for (int nb = 0; nb < 4; ++nb) s_v[px][nb][tid] = va[px][nb] + bv;
        __syncthreads();
    }
#pragma unroll
    for (int it = 0; it < 2; ++it) {
        int item = it * 128 + tid;
        int px = item >> 5, nb = (item >> 3) & 3, h = item & 7;
        const float* qp = &s_q[px][h * 16];
        const float* kp = &s_k[px][nb][h * 16];
        float s = 0.f;
#pragma unroll
        for (int dd = 0; dd < 16; dd += 4) {
            float4 aa = *(const float4*)&qp[dd];
            float4 bb = *(const float4*)&kp[dd];
            s += aa.x * bb.x + aa.y * bb.y + aa.z * bb.z + aa.w * bb.w;
        }
        s_att[px][nb][h] = s * 0.25f;
    }
    __syncthreads();
    if (tid < 64) {
        int px = tid >> 3, h = tid & 7;
        float l0 = s_att[px][0][h], l1 = s_att[px][1][h], l2 = s_att[px][2][h], l3 = s_att[px][3][h];
        float m = fmaxf(fmaxf(l0, l1), fmaxf(l2, l3));
        float e0 = __expf(l0 - m), e1 = __expf(l1 - m), e2 = __expf(l2 - m), e3 = __expf(l3 - m);
        float inv = 1.f / (e0 + e1 + e2 + e3);
        s_att[px][0][h] = e0 * inv; s_att[px][1][h] = e1 * inv;
        s_att[px][2][h] = e2 * inv; s_att[px][3][h] = e3 * inv;
    }
    __syncthreads();
    {
        int h = tid >> 4;
        float ov[8];
#pragma unroll
        for (int px = 0; px < 8; ++px) {
            ov[px] = s_att[px][0][h] * s_v[px][0][tid] + s_att[px][1][h] * s_v[px][1][tid] +
                     s_att[px][2][h] * s_v[px][2][tid] + s_att[px][3][h] * s_v[px][3][tid];
        }
        __syncthreads();
#pragma unroll
        for (int px = 0; px < 8; ++px) s_q[px][tid] = ov[px];
        __syncthreads();
    }
    {
        float oa[8];
#pragma unroll
        for (int i = 0; i < 8; ++i) oa[i] = 0.f;
        for (int j = 0; j < 128; j += 4) {
            float w0 = wo_t[(j    ) * 128 + tid];
            float w1 = wo_t[(j + 1) * 128 + tid];
            float w2 = wo_t[(j + 2) * 128 + tid];
            float w3 = wo_t[(j + 3) * 128 + tid];
#pragma unroll
            for (int px = 0; px < 8; ++px) {
                const float4 x = *(const float4*)&s_q[px][j];
                oa[px] = fmaf(w0, x.x, fmaf(w1, x.y, fmaf(w2, x.z, fmaf(w3, x.w, oa[px]))));
            }
        }
        float bo = wo_b[tid];
#pragma unroll
        for (int px = 0; px < 8; ++px)
            outp[(i64)b * obs + (i64)tid * ocs + (p0 + px)] = oa[px] + bo;
    }
}

// ---------------------------------------------------------------- generic linear
__global__ void linear_k(
    const float* __restrict__ X, i64 xb, i64 xl, i64 xk, int kmajor,
    const float* __restrict__ Wt, const float* __restrict__ bias,
    float* __restrict__ Y, int Lr, int K, int O, int act)
{
    extern __shared__ float sx[];
    const int tid = threadIdx.x;
    const int r0 = blockIdx.x * 16;
    const int b = r0 / Lr; const int l0 = r0 - b * Lr;
    const int stride = K + 4;
    for (int idx = tid; idx < 16 * K; idx += blockDim.x) {
        int p, k;
        if (kmajor) { k = idx >> 4; p = idx & 15; }
        else { p = idx / K; k = idx - p * K; }
        sx[p * stride + k] = X[(i64)b * xb + (i64)(l0 + p) * xl + (i64)k * xk];
    }
    __syncthreads();
    if (tid < O) {
        float acc[16];
#pragma unroll
        for (int i = 0; i < 16; ++i) acc[i] = 0.f;
        for (int j = 0; j < K; j += 4) {
            float w0 = Wt[(i64)(j    ) * O + tid];
            float w1 = Wt[(i64)(j + 1) * O + tid];
            float w2 = Wt[(i64)(j + 2) * O + tid];
            float w3 = Wt[(i64)(j + 3) * O + tid];
#pragma unroll
            for (int p = 0; p < 16; ++p) {
                const float4 x = *(const float4*)&sx[p * stride + j];
                acc[p] = fmaf(w0, x.x, fmaf(w1, x.y, fmaf(w2, x.z, fmaf(w3, x.w, acc[p]))));
            }
        }
        float bv = bias ? bias[tid] : 0.f;
#pragma unroll
        for (int p = 0; p < 16; ++p) {
            float v = acc[p] + bv;
            if (act == 1) v = fmaxf(v, 0.f) + log1pf(expf(-fabsf(v)));
            Y[(i64)(r0 + p) * O + tid] = v;
        }
    }
}

// ---------------------------------------------------------------- mamba causal conv1d + silu
__global__ void conv1d_k(const float* __restrict__ xz, const float* __restrict__ cw,
                         const float* __restrict__ cb, float* __restrict__ xs)
{
    i64 idx = (i64)blockIdx.x * blockDim.x + threadIdx.x;
    if (idx >= (i64)NB * LSEQ * 128) return;
    int d = (int)(idx & 127);
    i64 r = idx >> 7;
    i64 l = r % LSEQ;
    float v = cb[d] + cw[d * 3 + 2] * xz[r * 256 + d];
    if (l >= 1) v += cw[d * 3 + 1] * xz[(r - 1) * 256 + d];
    if (l >= 2) v += cw[d * 3    ] * xz[(r - 2) * 256 + d];
    xs[r * 128 + d] = v / (1.f + expf(-v));
}

// ---------------------------------------------------------------- chunked selective scan
__global__ __launch_bounds__(256) void scan1_k(
    const float* __restrict__ dtb, const float* __restrict__ xsb,
    const float* __restrict__ dbc, const float* __restrict__ Alog,
    float* __restrict__ HEND, float* __restrict__ SDT)
{
    const int tid = threadIdx.x;
    const int pair = blockIdx.x * 16 + (tid >> 4);
    const int s = tid & 15;
    const int b = pair >> 7, d = pair & 127;
    const int ch = blockIdx.y;
    const i64 lbase = (i64)b * LSEQ + (i64)ch * LCHUNK;
    const float a2 = -expf(Alog[d * 16 + s]) * 1.4426950408889634f;
    const float* dtp = dtb + lbase * 128 + d;
    const float* xsp = xsb + lbase * 128 + d;
    const float* Bp  = dbc + lbase * 40 + 8 + s;
    float h = 0.f, sdt = 0.f;
    for (int t = 0; t < LCHUNK; ++t) {
        float dtv = dtp[(i64)t * 128];
        float xsv = xsp[(i64)t * 128];
        float Bv  = Bp[(i64)t * 40];
        h = fmaf(exp2f(dtv * a2), h, dtv * xsv * Bv);
        sdt += dtv;
    }
    HEND[(((i64)b * NCHUNK + ch) * 128 + d) * 16 + s] = h;
    if (s == 0) SDT[((i64)b * NCHUNK + ch) * 128 + d] = sdt;
}

__global__ void scan2_k(const float* __restrict__ HEND, const float* __restrict__ SDT,
                        const float* __restrict__ Alog, float* __restrict__ HSTART)
{
    int idx = blockIdx.x * 256 + threadIdx.x;
    int b = idx >> 11, d = (idx >> 4) & 127, s = idx & 15;
    float a2 = -expf(Alog[d * 16 + s]) * 1.4426950408889634f;
    float hs = 0.f;
    for (int ch = 0; ch < NCHUNK; ++ch) {
        i64 base = ((i64)b * NCHUNK + ch) * 128 + d;
        HSTART[base * 16 + s] = hs;
        hs = fmaf(exp2f(SDT[base] * a2), hs, HEND[base * 16 + s]);
    }
}

__global__ __launch_bounds__(256) void scan3_k(
    float* __restrict__ dtb,
    const float* __restrict__ xsb, const float* __restrict__ dbc,
    const float* __restrict__ Alog, const float* __restrict__ HSTART,
    const float* __restrict__ xz, const float* __restrict__ Dp)
{
    const int tid = threadIdx.x;
    const int pair = blockIdx.x * 16 + (tid >> 4);
    const int s = tid & 15;
    const int b = pair >> 7, d = pair & 127;
    const int ch = blockIdx.y;
    const i64 lbase = (i64)b * LSEQ + (i64)ch * LCHUNK;
    const float a2 = -expf(Alog[d * 16 + s]) * 1.4426950408889634f;
    float* dtp = dtb + lbase * 128 + d;
    const float* xsp = xsb + lbase * 128 + d;
    const float* Bp  = dbc + lbase * 40 + 8 + s;
    const float* Cp  = dbc + lbase * 40 + 24 + s;
    float h = HSTART[(((i64)b * NCHUNK + ch) * 128 + d) * 16 + s];
    const float dp = Dp[d];
    for (int t = 0; t < LCHUNK; ++t) {
        float dtv = dtp[(i64)t * 128];
        float xsv = xsp[(i64)t * 128];
        float Bv  = Bp[(i64)t * 40];
        float Cv  = Cp[(i64)t * 40];
        h = fmaf(exp2f(dtv * a2), h, dtv * xsv * Bv);
        float yc = h * Cv;
        yc += __shfl_xor(yc, 1, 16);
        yc += __shfl_xor(yc, 2, 16);
        yc += __shfl_xor(yc, 4, 16);
        yc += __shfl_xor(yc, 8, 16);
        if (s == 0) {
            float zv = xz[(lbase + t) * 256 + 128 + d];
            float yf = (yc + xsv * dp) * (zv / (1.f + expf(-zv)));
            dtp[(i64)t * 128] = yf;
        }
    }
}

// ---------------------------------------------------------------- fused regroup + 1x1 conv + lrelu (+ bf16 out)
__global__ __launch_bounds__(128) void conv1x1_k(
    const float* __restrict__ mo, const float* __restrict__ w1t,
    const float* __restrict__ b1, float* __restrict__ out128, short* __restrict__ toutb)
{
    __shared__ float sx[4][896];
    const int tid = threadIdx.x;
    const int b = blockIdx.y;
    const int p0 = blockIdx.x * 4;
#pragma unroll
    for (int px = 0; px < 4; ++px) {
        int p = p0 + px;
#pragma unroll
        for (int t = 0; t < 7; ++t)
            sx[px][tid * 7 + t] = mo[((i64)b * LSEQ + t * HW + p) * 128 + tid];
    }
    __syncthreads();
    float acc[4] = {0.f, 0.f, 0.f, 0.f};
    for (int j = 0; j < 896; j += 4) {
        float w0 = w1t[(j    ) * 128 + tid];
        float w1 = w1t[(j + 1) * 128 + tid];
        float w2 = w1t[(j + 2) * 128 + tid];
        float w3 = w1t[(j + 3) * 128 + tid];
#pragma unroll
        for (int px = 0; px < 4; ++px) {
            const float4 x = *(const float4*)&sx[px][j];
            acc[px] = fmaf(w0, x.x, fmaf(w1, x.y, fmaf(w2, x.z, fmaf(w3, x.w, acc[px]))));
        }
    }
    float bv = b1[tid];
#pragma unroll
    for (int px = 0; px < 4; ++px) {
        float v = lrelu_f(acc[px] + bv);
        out128[((i64)b * 128 + tid) * HW + (p0 + px)] = v;
        toutb[((i64)b * HW + p0 + px) * 128 + tid] = bf16r(v);
    }
}

// ================================================================ host
extern "C" void kernel_launch(void* const* d_in, const int* in_sizes, int n_in,
                              void* d_out, int out_size, void* d_ws, size_t ws_size,
                              hipStream_t stream) {
    (void)in_sizes; (void)n_in; (void)out_size; (void)ws_size;
    const float* Lin[7];
    for (int i = 0; i < 7; ++i) Lin[i] = (const float*)d_in[i];
    const float* conv_rec_w = (const float*)d_in[7];
    const float* conv_rec_b = (const float*)d_in[8];
    const float* conv3_w    = (const float*)d_in[9];
    const float* conv3_b    = (const float*)d_in[10];
    const float* conv1x1_w  = (const float*)d_in[11];
    const float* conv1x1_b  = (const float*)d_in[12];
    const float* conv13_w   = (const float*)d_in[13];
    const float* conv13_b   = (const float*)d_in[14];
    const float* wq_w = (const float*)d_in[15]; const float* wq_b = (const float*)d_in[16];
    const float* wk_w = (const float*)d_in[17]; const float* wk_b = (const float*)d_in[18];
    const float* wv_w = (const float*)d_in[19]; const float* wv_b = (const float*)d_in[20];
    const float* wo_w = (const float*)d_in[21]; const float* wo_b = (const float*)d_in[22];
    const float* m_in_w    = (const float*)d_in[23];
    const float* m_conv_w  = (const float*)d_in[24];
    const float* m_conv_b  = (const float*)d_in[25];
    const float* m_xproj_w = (const float*)d_in[26];
    const float* m_dt_w    = (const float*)d_in[27];
    const float* m_dt_b    = (const float*)d_in[28];
    const float* m_Alog    = (const float*)d_in[29];
    const float* m_D       = (const float*)d_in[30];
    const float* m_out_w   = (const float*)d_in[31];
    const float* spy1_w = (const float*)d_in[32]; const float* spy1_b = (const float*)d_in[33];
    const float* spy2_w = (const float*)d_in[34]; const float* spy2_b = (const float*)d_in[35];
    float* out = (float*)d_out;
    float* W = (float*)d_ws;

    Ptr7 P7; for (int i = 0; i < 7; ++i) P7.p[i] = Lin[i];

    // -------- workspace layout (floats)
    i64 off = 0;
    float* FEATS  = W + off; off += (i64)TF * NB * CH * HW;
    float* FEATS5 = W + off; off += (i64)NB * CH * TF * HW;
    float* XZ     = W + off; off += (i64)NB * LSEQ * 256;
    float* XS     = W + off; off += (i64)NB * LSEQ * 128;
    float* DBC    = W + off; off += (i64)NB * LSEQ * 40;
    float* DT     = W + off; off += (i64)NB * LSEQ * 128;
    float* OUT128 = W + off; off += (i64)NB * 128 * HW;
    float* WQ_T = W + off; off += 16384;
    float* WK_T = W + off; off += 16384;
    float* WV_T = W + off; off += 16384;
    float* WO_T = W + off; off += 16384;
    float* MIN_T  = W + off; off += 256 * 128;
    float* MXP_T  = W + off; off += 40 * 128;
    float* MDT_T  = W + off; off += 128 * 8;
    float* MOUT_T = W + off; off += 16384;
    float* W1_T   = W + off; off += 128 * 896;
    float* LQS  = W + off; off += (i64)NB * TF * 3 * HW;
    float* P1_0 = W + off; off += 12 * 3 * HW;
    float* P2_0 = W + off; off += 12 * 3 * HW;
    float* P1_1 = W + off; off += 12 * 3 * 1024;
    float* P2_1 = W + off; off += 12 * 3 * 1024;
    float* P1_2 = W + off; off += 12 * 3 * 256;
    float* P2_2 = W + off; off += 12 * 3 * 256;
    float* FLOW2 = W + off; off += 12 * 2 * 256;
    float* FLOW1 = W + off; off += 12 * 2 * 1024;
    float* FLOW0 = W + off; off += 12 * 2 * HW;
    float* INP = W + off; off += 12 * 8 * HW;
    float* HHB = W + off; off += 12 * 32 * HW;
    float* HEND   = W + off; off += (i64)NB * NCHUNK * 128 * 16;
    float* HSTART = W + off; off += (i64)NB * NCHUNK * 128 * 16;
    float* SDT    = W + off; off += (i64)NB * NCHUNK * 128;
    float* MO = XZ;
    // -------- bf16 region (shorts) carved after float region
    short* SBASE = (short*)(W + off);
    i64 soff = 0;
    short* TIN    = SBASE + soff; soff += (i64)14 * HW * 128;
    short* TFEATS = SBASE + soff; soff += (i64)14 * HW * 128;
    short* TOUT   = SBASE + soff; soff += (i64)NB * HW * 128;
    short* WB3    = SBASE + soff; soff += (i64)9 * 2 * 8192;
    short* WB13   = SBASE + soff; soff += (i64)9 * 4 * 8192;

    // -------- weight transposes / preps
    auto T = [&](const float* src, float* dst, int R, int Cc) {
        transpose_k<<<cdiv((i64)R * Cc, 256), 256, 0, stream>>>(src, dst, R, Cc);
    };
    T(wq_w, WQ_T, 128, 128); T(wk_w, WK_T, 128, 128);
    T(wv_w, WV_T, 128, 128); T(wo_w, WO_T, 128, 128);
    T(m_in_w, MIN_T, 256, 128); T(m_xproj_w, MXP_T, 40, 128);
    T(m_dt_w, MDT_T, 128, 8);   T(m_out_w, MOUT_T, 128, 128);
    T(conv1x1_w, W1_T, 128, 896);
    wprep_k<<<cdiv(9 * 2 * 8192, 256), 256, 0, stream>>>(conv3_w, WB3, 128, 2);
    wprep_k<<<cdiv(9 * 4 * 8192, 256), 256, 0, stream>>>(conv13_w, WB13, 256, 4);
    tprep_k<<<dim3(32, 14), 256, 0, stream>>>(P7, TIN);

    // -------- conv_rec (all frames, fp32) -> LQS
    convrec_k<<<dim3(16, 14), 256, 0, stream>>>(P7, conv_rec_w, conv_rec_b, LQS);

    // -------- conv3 (all frames, MFMA bf16) -> FEATS fp32 + TFEATS bf16
    {
        Ptr7 none; for (int i = 0; i < 7; ++i) none.p[i] = nullptr;
        convmfma_k<<<dim3(32, 14), 256, 0, stream>>>(
            TIN, nullptr, 2, 2, WB3, conv3_b, none, 0, FEATS, TFEATS, 1);
    }

    // -------- spynet
    copy_pyr_k<<<cdiv(12 * 3 * HW, 256), 256, 0, stream>>>(LQS, P1_0, 0);
    copy_pyr_k<<<cdiv(12 * 3 * HW, 256), 256, 0, stream>>>(LQS, P2_0, 1);
    avgpool_k<<<cdiv(36 * 32 * 32, 256), 256, 0, stream>>>(P1_0, P1_1, 36, 64, 64);
    avgpool_k<<<cdiv(36 * 32 * 32, 256), 256, 0, stream>>>(P2_0, P2_1, 36, 64, 64);
    avgpool_k<<<cdiv(36 * 16 * 16, 256), 256, 0, stream>>>(P1_1, P1_2, 36, 32, 32);
    avgpool_k<<<cdiv(36 * 16 * 16, 256), 256, 0, stream>>>(P2_1, P2_2, 36, 32, 32);
    hipMemsetAsync(FLOW2, 0, 12 * 2 * 256 * sizeof(float), stream);

    struct Lvl { float *p1, *p2, *fl; int hw_; };
    Lvl lv[3] = { {P1_2, P2_2, FLOW2, 16}, {P1_1, P2_1, FLOW1, 32}, {P1_0, P2_0, FLOW0, 64} };
    for (int li = 0; li < 3; ++li) {
        int hl = lv[li].hw_;
        int hw = hl * hl;
        int tiles = (hl / 16) * (hl / 16);
        build_inp_k<<<cdiv(12 * hw, 256), 256, 0, stream>>>(lv[li].p1, lv[li].p2, lv[li].fl, INP, hl, hl);
        conv3x3_k<<<dim3(tiles, 2, 12), 256, 0, stream>>>(
            INP, 8, (i64)8 * hw, nullptr, 0, 0, spy1_w, spy1_b, 32, hl, hl,
            nullptr, 0, HHB, (i64)32 * hw, 1);
        conv3x3_k<<<dim3(tiles, 1, 12), 256, 0, stream>>>(
            HHB, 32, (i64)32 * hw, nullptr, 0, 0, spy2_w, spy2_b, 2, hl, hl,
            lv[li].fl, (i64)2 * hw, lv[li].fl, (i64)2 * hw, 0);
        if (li < 2) {
            int ho = hl * 2;
            resize_flow_k<<<cdiv(12 * 2 * ho * ho, 256), 256, 0, stream>>>(lv[li].fl, lv[li + 1].fl, hl, hl);
        }
    }

    // -------- propagation
    copy_slot0_k<<<cdiv((i64)NB * CH * HW, 256), 256, 0, stream>>>(FEATS + 6LL * NB * CH * HW, FEATS5);
    for (int i = 1; i <= 6; ++i) {
        int fidx = 6 - i;
        const float* cur = FEATS + (i64)fidx * NB * CH * HW;
        const float* prop; i64 pbs, pcs;
        if (i == 1) { prop = FEATS + 6LL * NB * CH * HW; pbs = (i64)CH * HW; pcs = HW; }
        else { prop = FEATS5 + (i64)(i - 1) * HW; pbs = (i64)CH * TF * HW; pcs = (i64)TF * HW; }
        attn_k<<<dim3(512, 2), 128, 0, stream>>>(
            prop, pbs, pcs, cur, FLOW0, fidx,
            WQ_T, wq_b, WK_T, wk_b, WV_T, wv_b, WO_T, wo_b,
            FEATS5 + (i64)i * HW, (i64)CH * TF * HW, (i64)TF * HW);
    }

    // -------- mamba
    const int nrow_blocks = (NB * LSEQ) / 16;
    linear_k<<<nrow_blocks, 256, 16 * (128 + 4) * 4, stream>>>(
        FEATS5, (i64)CH * LSEQ, 1, LSEQ, 1, MIN_T, nullptr, XZ, LSEQ, 128, 256, 0);
    conv1d_k<<<cdiv((i64)NB * LSEQ * 128, 256), 256, 0, stream>>>(XZ, m_conv_w, m_conv_b, XS);
    linear_k<<<nrow_blocks, 64, 16 * (128 + 4) * 4, stream>>>(
        XS, (i64)LSEQ * 128, 128, 1, 0, MXP_T, nullptr, DBC, LSEQ, 128, 40, 0);
    linear_k<<<nrow_blocks, 128, 16 * (8 + 4) * 4, stream>>>(
        DBC, (i64)LSEQ * 40, 40, 1, 0, MDT_T, m_dt_b, DT, LSEQ, 8, 128, 1);
    scan1_k<<<dim3(16, NCHUNK), 256, 0, stream>>>(DT, XS, DBC, m_Alog, HEND, SDT);
    scan2_k<<<16, 256, 0, stream>>>(HEND, SDT, m_Alog, HSTART);
    scan3_k<<<dim3(16, NCHUNK), 256, 0, stream>>>(DT, XS, DBC, m_Alog, HSTART, XZ, m_D);
    linear_k<<<nrow_blocks, 128, 16 * (128 + 4) * 4, stream>>>(
        DT, (i64)LSEQ * 128, 128, 1, 0, MOUT_T, nullptr, MO, LSEQ, 128, 128, 0);
    conv1x1_k<<<dim3(1024, 2), 128, 0, stream>>>(MO, W1_T, conv1x1_b, OUT128, TOUT);

    // -------- conv13 (all frames, MFMA bf16) + residual -> d_out
    convmfma_k<<<dim3(32, 14), 256, 0, stream>>>(
        TFEATS, TOUT, 4, 2, WB13, conv13_b, P7, 1, out, nullptr, 1);
}

// Round 5
// 1322.211 us; speedup vs baseline: 3.9233x; 1.2225x over previous
//
#include <hip/hip_runtime.h>
#include <hip/hip_bf16.h>
#include <math.h>

// Problem constants
#define NB   2        // batch N
#define CH   128      // C
#define HT   64
#define WD   64
#define HW   4096     // H*W
#define TF   7        // frames
#define LSEQ 28672    // 7*4096
#define NCHUNK 448    // mamba scan chunks (per batch)
#define LCHUNK 64     // 448*64 = 28672

typedef long long i64;
typedef float f32x4 __attribute__((ext_vector_type(4)));
typedef short sv8 __attribute__((ext_vector_type(8)));
typedef short sv4 __attribute__((ext_vector_type(4)));

struct Ptr7 { const float* p[7]; };

static inline int cdiv(i64 a, int b) { return (int)((a + b - 1) / b); }

__device__ __forceinline__ float lrelu_f(float v) { return v >= 0.f ? v : 0.1f * v; }

__device__ __forceinline__ short bf16r(float f) {
    unsigned u = __float_as_uint(f);
    unsigned r = (u + 0x7FFFu + ((u >> 16) & 1u)) >> 16;
    return (short)r;
}

// ---------------------------------------------------------------- transpose (small weights)
__global__ void transpose_k(const float* __restrict__ src, float* __restrict__ dst, int R, int Cc) {
    i64 idx = (i64)blockIdx.x * blockDim.x + threadIdx.x;
    if (idx >= (i64)R * Cc) return;
    int r = (int)(idx / Cc), c = (int)(idx - (i64)r * Cc);
    dst[(i64)c * R + r] = src[idx];
}

// ---------------------------------------------------------------- weight prep for MFMA conv (3x3)
__global__ void wprep_k(const float* __restrict__ w, short* __restrict__ wb, int CinT, int CC) {
    int idx = blockIdx.x * 256 + threadIdx.x;
    int total = 9 * CC * 8192;
    if (idx >= total) return;
    int e   = idx & 7;
    int cgp = (idx >> 3) & 7;
    int co  = (idx >> 6) & 127;
    int rest = idx >> 13;            // k9*CC + cc
    int cc = rest % CC, k9 = rest / CC;
    int cg = cgp ^ (co & 7);
    int ci = cc * 64 + cg * 8 + e;
    wb[idx] = bf16r(w[((i64)co * CinT + ci) * 9 + k9]);
}

// ---------------------------------------------------------------- weight prep for MFMA GEMM
__global__ void wgprep_k(const float* __restrict__ w, short* __restrict__ wb,
                         int K, int O, int nblk, int kmapmode, int total) {
    int idx = blockIdx.x * 256 + threadIdx.x;
    if (idx >= total) return;
    int e = idx & 7;
    int cgp = (idx >> 3) & 7;
    int co = (idx >> 6) & 127;
    int chunk = idx >> 13;
    int blk = chunk % nblk, kc = chunk / nblk;
    int cop = blk * 128 + co;
    int k = kc * 64 + ((cgp ^ (co & 7)) * 8) + e;
    float v = 0.f;
    if (cop < O && k < K) {
        int sk = (kmapmode == 1) ? ((k & 127) * 7 + (k >> 7)) : k;
        v = w[(i64)cop * K + sk];
    }
    wb[idx] = bf16r(v);
}

// ---------------------------------------------------------------- input transpose: fp32 [b][ci][p] -> bf16 [z][p][ci]
__global__ __launch_bounds__(256) void tprep_k(Ptr7 lin, short* __restrict__ tin) {
    __shared__ short st[128 * 130];
    const int tid = threadIdx.x;
    const int pg = blockIdx.x;       // 32 groups of 128 px
    const int z = blockIdx.y; const int t = z >> 1, b = z & 1;
    const float* src = lin.p[t] + (i64)b * 128 * HW + pg * 128;
    int p_ = tid & 127, cihalf = tid >> 7;
    for (int ci0 = 0; ci0 < 128; ci0 += 2) {
        int ci = ci0 + cihalf;
        st[p_ * 130 + ci] = bf16r(src[(i64)ci * HW + p_]);
    }
    __syncthreads();
    for (int it = 0; it < 32; ++it) {
        int o = it * 256 + tid;              // 8192 int units
        int p = o >> 6, cp = o & 63;
        *(int*)&tin[((i64)z * HW + pg * 128 + p) * 128 + cp * 2] = *(int*)&st[p * 130 + cp * 2];
    }
}

// ---------------------------------------------------------------- slot0: FEATS[6] fp32 [b][c][p] -> TF5 bf16 [(b*7+0)*HW+p][c]
__global__ __launch_bounds__(256) void slot0_k(const float* __restrict__ f6, short* __restrict__ tf5) {
    __shared__ short st[128 * 130];
    const int tid = threadIdx.x;
    const int pg = blockIdx.x;
    const int b = blockIdx.y;
    const float* src = f6 + (i64)b * 128 * HW + pg * 128;
    int p_ = tid & 127, chalf = tid >> 7;
    for (int c0 = 0; c0 < 128; c0 += 2) {
        int c = c0 + chalf;
        st[p_ * 130 + c] = bf16r(src[(i64)c * HW + p_]);
    }
    __syncthreads();
    short* dst = tf5 + ((i64)(b * 7) * HW + (i64)pg * 128) * 128;
    for (int it = 0; it < 32; ++it) {
        int o = it * 256 + tid;
        int p = o >> 6, cp = o & 63;
        *(int*)&dst[(i64)p * 128 + cp * 2] = *(int*)&st[p * 130 + cp * 2];
    }
}

// ---------------------------------------------------------------- MFMA 3x3 conv (pad=1), implicit GEMM
__global__ __launch_bounds__(256) void convmfma_k(
    const short* __restrict__ srcA, const short* __restrict__ srcB, int CC, int chA,
    const short* __restrict__ WB, const float* __restrict__ bias,
    Ptr7 res, int has_res,
    float* __restrict__ outf, short* __restrict__ outb, int relu)
{
    __shared__ short SA[264 * 64];   // [pos][cg'*8], cg' = cg ^ (pos&7)
    __shared__ short SB[128 * 64];   // [co][cg'*8],  cg' = cg ^ (co&7)
    const int tid = threadIdx.x;
    const int rp = blockIdx.x;       // rowpair 0..31
    const int z = blockIdx.y;        // 0..13
    const int t = z >> 1, b = z & 1;
    const int y0 = rp * 2;
    const int pbase = rp * 128;
    const int lane = tid & 63, wv = tid >> 6;
    const int wm = wv & 1, wn = wv >> 1;
    const int l15 = lane & 15, l4 = lane >> 4;

    f32x4 acc[4][4];
    f32x4 zz = {0.f, 0.f, 0.f, 0.f};
#pragma unroll
    for (int i = 0; i < 4; ++i)
#pragma unroll
        for (int j = 0; j < 4; ++j) acc[i][j] = zz;

    for (int cc = 0; cc < CC; ++cc) {
        __syncthreads();
        {
            const short* sp = (cc < chA) ? srcA + (i64)z * HW * 128 + cc * 64
                                         : srcB + (i64)b * HW * 128 + (cc - chA) * 64;
            int cg = tid & 7;
            for (int it = 0; it < 9; ++it) {
                int pos = it * 32 + (tid >> 3);
                if (pos < 264) {
                    int r = pos / 66, ccol = pos - r * 66;
                    int gy = y0 - 1 + r, gx = ccol - 1;
                    int4 val = {0, 0, 0, 0};
                    if (gy >= 0 && gy < 64 && gx >= 0 && gx < 64)
                        val = *(const int4*)(sp + ((i64)(gy * 64 + gx)) * 128 + cg * 8);
                    *(int4*)&SA[pos * 64 + ((cg ^ (pos & 7)) * 8)] = val;
                }
            }
        }
        for (int k9 = 0; k9 < 9; ++k9) {
            __syncthreads();
            {
                const short* wsrc = WB + ((i64)(k9 * CC + cc)) * 8192;
                for (int it = 0; it < 4; ++it) {
                    int o = it * 256 + tid;
                    *(int4*)&SB[o * 8] = *(const int4*)(wsrc + o * 8);
                }
            }
            __syncthreads();
            const int ky = k9 / 3, kx = k9 - ky * 3;
#pragma unroll
            for (int ks = 0; ks < 2; ++ks) {
                sv8 af[4], bf_[4];
                int cgk = ks * 4 + l4;
#pragma unroll
                for (int mt = 0; mt < 4; ++mt) {
                    int co = wm * 64 + mt * 16 + l15;
                    af[mt] = *(const sv8*)&SB[co * 64 + ((cgk ^ (co & 7)) * 8)];
                }
#pragma unroll
                for (int nt = 0; nt < 4; ++nt) {
                    int pos = (wn + ky) * 66 + nt * 16 + l15 + kx;
                    bf_[nt] = *(const sv8*)&SA[pos * 64 + ((cgk ^ (pos & 7)) * 8)];
                }
#pragma unroll
                for (int mt = 0; mt < 4; ++mt)
#pragma unroll
                    for (int nt = 0; nt < 4; ++nt)
                        acc[mt][nt] = __builtin_amdgcn_mfma_f32_16x16x32_bf16(af[mt], bf_[nt], acc[mt][nt], 0, 0, 0);
            }
        }
    }
    const float* rptr = has_res ? (res.p[t] + (i64)b * 128 * HW) : nullptr;
#pragma unroll
    for (int mt = 0; mt < 4; ++mt) {
        int co0 = wm * 64 + mt * 16 + l4 * 4;
#pragma unroll
        for (int nt = 0; nt < 4; ++nt) {
            int pix = pbase + wn * 64 + nt * 16 + l15;
            float vv[4];
#pragma unroll
            for (int r = 0; r < 4; ++r) {
                float x = acc[mt][nt][r] + bias[co0 + r];
                if (relu) x = lrelu_f(x);
                if (rptr) x += rptr[(i64)(co0 + r) * HW + pix];
                outf[((i64)z * 128 + co0 + r) * HW + pix] = x;
                vv[r] = x;
            }
            if (outb) {
                sv4 pk;
#pragma unroll
                for (int r = 0; r < 4; ++r) pk[r] = bf16r(vv[r]);
                *(sv4*)&outb[((i64)z * HW + pix) * 128 + co0] = pk;
            }
        }
    }
}

// ---------------------------------------------------------------- MFMA GEMM: C[row][co'] = A[row][k] * W[co'][k]^T
// modes: 0 = fp32 out[row*ldo + blk*128+co] (+bias, mask co<Ovalid)
//        1 = bf16 regroup (out-proj -> MO2 [b*HW+p][896])
//        2 = bf16 out[row*128+co] with bias+lrelu (conv1x1 -> TOUT)
__global__ __launch_bounds__(256) void gemm_k(
    const short* __restrict__ A, i64 lda, int Kc, int nblk,
    const short* __restrict__ WB, const float* __restrict__ bias, int Ovalid,
    float* __restrict__ outf, i64 ldo,
    short* __restrict__ outb, int mode)
{
    __shared__ short SA[128 * 64];
    __shared__ short SB[128 * 64];
    const int tid = threadIdx.x;
    const i64 row0 = (i64)blockIdx.x * 128;
    const int blk = blockIdx.y;
    const int lane = tid & 63, wv = tid >> 6;
    const int wm = wv & 1, wn = wv >> 1;
    const int l15 = lane & 15, l4 = lane >> 4;

    f32x4 acc[4][4];
    f32x4 zz = {0.f, 0.f, 0.f, 0.f};
#pragma unroll
    for (int i = 0; i < 4; ++i)
#pragma unroll
        for (int j = 0; j < 4; ++j) acc[i][j] = zz;

    for (int kc = 0; kc < Kc; ++kc) {
        __syncthreads();
        {
            const short* ap = A + row0 * lda + kc * 64;
#pragma unroll
            for (int it = 0; it < 4; ++it) {
                int idx = it * 256 + tid;
                int r = idx >> 3, cg = idx & 7;
                int4 val = *(const int4*)(ap + (i64)r * lda + cg * 8);
                *(int4*)&SA[r * 64 + ((cg ^ (r & 7)) * 8)] = val;
            }
            const short* wsrc = WB + (i64)(kc * nblk + blk) * 8192;
#pragma unroll
            for (int it = 0; it < 4; ++it) {
                int o = it * 256 + tid;
                *(int4*)&SB[o * 8] = *(const int4*)(wsrc + o * 8);
            }
        }
        __syncthreads();
#pragma unroll
        for (int ks = 0; ks < 2; ++ks) {
            sv8 af[4], bfr[4];
            int cgk = ks * 4 + l4;
#pragma unroll
            for (int mt = 0; mt < 4; ++mt) {
                int co = wm * 64 + mt * 16 + l15;
                af[mt] = *(const sv8*)&SB[co * 64 + ((cgk ^ (co & 7)) * 8)];
            }
#pragma unroll
            for (int nt = 0; nt < 4; ++nt) {
                int rr = wn * 64 + nt * 16 + l15;
                bfr[nt] = *(const sv8*)&SA[rr * 64 + ((cgk ^ (rr & 7)) * 8)];
            }
#pragma unroll
            for (int mt = 0; mt < 4; ++mt)
#pragma unroll
                for (int nt = 0; nt < 4; ++nt)
                    acc[mt][nt] = __builtin_amdgcn_mfma_f32_16x16x32_bf16(af[mt], bfr[nt], acc[mt][nt], 0, 0, 0);
        }
    }
#pragma unroll
    for (int mt = 0; mt < 4; ++mt) {
        int co0 = wm * 64 + mt * 16 + l4 * 4;
#pragma unroll
        for (int nt = 0; nt < 4; ++nt) {
            i64 row = row0 + wn * 64 + nt * 16 + l15;
#pragma unroll
            for (int r = 0; r < 4; ++r) {
                int c = co0 + r;
                float v = acc[mt][nt][r];
                if (mode == 0) {
                    if (c < Ovalid) {
                        if (bias) v += bias[blk * 128 + c];
                        outf[row * ldo + blk * 128 + c] = v;
                    }
                } else if (mode == 1) {
                    int b = (int)(row / LSEQ); int rem = (int)(row - (i64)b * LSEQ);
                    int t7 = rem >> 12, p = rem & 4095;
                    outb[((i64)(b * HW + p)) * 896 + t7 * 128 + c] = bf16r(v);
                } else {
                    v = lrelu_f(v + bias[c]);
                    outb[row * 128 + c] = bf16r(v);
                }
            }
        }
    }
}

// ---------------------------------------------------------------- conv_rec (128->3) fp32
__global__ __launch_bounds__(256) void convrec_k(Ptr7 lin, const float* __restrict__ w,
                                                 const float* __restrict__ bias, float* __restrict__ lqs) {
    __shared__ float s_in[16][18][18];
    __shared__ float s_w[3][16][9];
    const int tid = threadIdx.x;
    const int tx = tid & 15, ty = tid >> 4;
    const int tile = blockIdx.x;
    const int z = blockIdx.y; const int t = z >> 1, b = z & 1;
    const int tx0 = (tile & 3) << 4, ty0 = (tile >> 2) << 4;
    const float* in = lin.p[t] + (i64)b * 128 * HW;
    float acc[3] = {bias[0], bias[1], bias[2]};
    for (int ci0 = 0; ci0 < 128; ci0 += 16) {
        for (int idx = tid; idx < 16 * 324; idx += 256) {
            int chn = idx / 324; int r = idx - chn * 324;
            int iy = r / 18; int ix = r - iy * 18;
            int gy = ty0 + iy - 1, gx = tx0 + ix - 1;
            float v = 0.f;
            if (gy >= 0 && gy < 64 && gx >= 0 && gx < 64)
                v = in[(i64)(ci0 + chn) * HW + gy * 64 + gx];
            s_in[chn][iy][ix] = v;
        }
        for (int idx = tid; idx < 3 * 16 * 9; idx += 256) {
            int co = idx / 144; int r = idx - co * 144;
            int ci = r / 9; int k = r - ci * 9;
            s_w[co][ci][k] = w[((i64)co * 128 + ci0 + ci) * 9 + k];
        }
        __syncthreads();
#pragma unroll 4
        for (int ci = 0; ci < 16; ++ci) {
#pragma unroll
            for (int ky = 0; ky < 3; ++ky)
#pragma unroll
                for (int kx = 0; kx < 3; ++kx) {
                    float xv = s_in[ci][ty + ky][tx + kx];
#pragma unroll
                    for (int co = 0; co < 3; ++co)
                        acc[co] = fmaf(s_w[co][ci][ky * 3 + kx], xv, acc[co]);
                }
        }
        __syncthreads();
    }
    int p = (ty0 + ty) * 64 + tx0 + tx;
#pragma unroll
    for (int co = 0; co < 3; ++co)
        lqs[(i64)b * 21 * HW + (i64)t * 3 * HW + (i64)co * HW + p] = acc[co];
}

// ---------------------------------------------------------------- generic fp32 3x3 conv (spynet)
__global__ __launch_bounds__(256) void conv3x3_k(
    const float* __restrict__ in1, int Cin1, i64 in1_bs,
    const float* __restrict__ in2, int Cin2, i64 in2_bs,
    const float* __restrict__ w, const float* __restrict__ bias, int Cout,
    int H, int W,
    const float* __restrict__ res, i64 res_bs,
    float* __restrict__ out, i64 out_bs, int relu)
{
    __shared__ float s_in[16][18][18];
    __shared__ float s_w[16][9][16];
    const int tid = threadIdx.x;
    const int tx = tid & 15, ty = tid >> 4;
    const int tX = W >> 4;
    const int tx0 = (blockIdx.x % tX) << 4, ty0 = (blockIdx.x / tX) << 4;
    const int co0 = blockIdx.y << 4;
    const int z = blockIdx.z;
    const int CinT = Cin1 + Cin2;
    const i64 hw = (i64)H * W;

    float acc[16];
#pragma unroll
    for (int i = 0; i < 16; ++i) acc[i] = 0.f;

    for (int ci0 = 0; ci0 < CinT; ci0 += 16) {
        for (int idx = tid; idx < 16 * 324; idx += 256) {
            int chn = idx / 324; int r = idx - chn * 324;
            int iy = r / 18; int ix = r - iy * 18;
            int gy = ty0 + iy - 1, gx = tx0 + ix - 1;
            int ci = ci0 + chn;
            float v = 0.f;
            if (ci < CinT && gy >= 0 && gy < H && gx >= 0 && gx < W) {
                if (ci < Cin1) v = in1[(i64)z * in1_bs + (i64)ci * hw + gy * W + gx];
                else           v = in2[(i64)z * in2_bs + (i64)(ci - Cin1) * hw + gy * W + gx];
            }
            s_in[chn][iy][ix] = v;
        }
        for (int idx = tid; idx < 16 * 144; idx += 256) {
            int co = idx / 144; int r = idx - co * 144;
            int ci = r / 9; int k = r - ci * 9;
            float v = 0.f;
            int gco = co0 + co, gci = ci0 + ci;
            if (gco < Cout && gci < CinT) v = w[((i64)gco * CinT + gci) * 9 + k];
            s_w[ci][k][co] = v;
        }
        __syncthreads();
#pragma unroll 2
        for (int ci = 0; ci < 16; ++ci) {
#pragma unroll
            for (int ky = 0; ky < 3; ++ky) {
#pragma unroll
                for (int kx = 0; kx < 3; ++kx) {
                    float xv = s_in[ci][ty + ky][tx + kx];
                    const float4* wr = (const float4*)(&s_w[ci][ky * 3 + kx][0]);
                    float wv[16];
                    ((float4*)wv)[0] = wr[0];
                    ((float4*)wv)[1] = wr[1];
                    ((float4*)wv)[2] = wr[2];
                    ((float4*)wv)[3] = wr[3];
#pragma unroll
                    for (int co = 0; co < 16; ++co) acc[co] = fmaf(wv[co], xv, acc[co]);
                }
            }
        }
        __syncthreads();
    }
    int y = ty0 + ty, x = tx0 + tx;
#pragma unroll
    for (int co = 0; co < 16; ++co) {
        int gco = co0 + co;
        if (gco < Cout) {
            float v = acc[co] + bias[gco];
            if (relu) v = lrelu_f(v);
            if (res) v += res[(i64)z * res_bs + (i64)gco * hw + y * W + x];
            out[(i64)z * out_bs + (i64)gco * hw + y * W + x] = v;
        }
    }
}

// ---------------------------------------------------------------- spynet helpers
__global__ void copy_pyr_k(const float* __restrict__ lqs, float* __restrict__ dst, int shift) {
    int idx = blockIdx.x * blockDim.x + threadIdx.x;
    if (idx >= 12 * 3 * HW) return;
    int p = idx & 4095; int rest = idx >> 12; int c = rest % 3; int bf = rest / 3;
    int b = bf / 6, i = bf % 6;
    dst[idx] = lqs[(((i64)b * 7 + i + shift) * 3 + c) * HW + p];
}

__global__ void avgpool_k(const float* __restrict__ in, float* __restrict__ out, int nc, int hi, int wi) {
    int ho = hi >> 1, wo = wi >> 1;
    int idx = blockIdx.x * blockDim.x + threadIdx.x;
    if (idx >= nc * ho * wo) return;
    int x = idx % wo; int y = (idx / wo) % ho; int c = idx / (wo * ho);
    const float* ip = in + (i64)c * hi * wi;
    out[idx] = 0.25f * (ip[(2 * y) * wi + 2 * x] + ip[(2 * y) * wi + 2 * x + 1] +
                        ip[(2 * y + 1) * wi + 2 * x] + ip[(2 * y + 1) * wi + 2 * x + 1]);
}

__global__ void build_inp_k(const float* __restrict__ a, const float* __restrict__ b2,
                            const float* __restrict__ flow, float* __restrict__ inp, int hl, int wl) {
    int idx = blockIdx.x * blockDim.x + threadIdx.x;
    int hw = hl * wl;
    if (idx >= 12 * hw) return;
    int bf = idx / hw; int r = idx - bf * hw;
    int y = r / wl, x = r - y * wl;
    float fx = flow[((i64)bf * 2) * hw + r];
    float fy = flow[((i64)bf * 2 + 1) * hw + r];
    float sx = x + fx, sy = y + fy;
    float x0f = floorf(sx), y0f = floorf(sy);
    float dx = sx - x0f, dy = sy - y0f;
    int x0 = (int)fminf(fmaxf(x0f, 0.f), (float)(wl - 1));
    int x1 = (int)fminf(fmaxf(x0f + 1.f, 0.f), (float)(wl - 1));
    int y0 = (int)fminf(fmaxf(y0f, 0.f), (float)(hl - 1));
    int y1 = (int)fminf(fmaxf(y0f + 1.f, 0.f), (float)(hl - 1));
    float wa = (1.f - dx) * (1.f - dy), wb = (1.f - dx) * dy, wc = dx * (1.f - dy), wd = dx * dy;
    for (int c = 0; c < 3; ++c) {
        const float* src = b2 + ((i64)bf * 3 + c) * hw;
        float wv = wa * src[y0 * wl + x0] + wb * src[y1 * wl + x0] +
                   wc * src[y0 * wl + x1] + wd * src[y1 * wl + x1];
        inp[((i64)bf * 8 + c) * hw + r] = a[((i64)bf * 3 + c) * hw + r];
        inp[((i64)bf * 8 + 3 + c) * hw + r] = wv;
    }
    inp[((i64)bf * 8 + 6) * hw + r] = fx;
    inp[((i64)bf * 8 + 7) * hw + r] = fy;
}

__global__ void resize_flow_k(const float* __restrict__ in, float* __restrict__ out, int hi, int wi) {
    int ho = hi * 2, wo = wi * 2;
    int idx = blockIdx.x * blockDim.x + threadIdx.x;
    if (idx >= 12 * 2 * ho * wo) return;
    int x = idx % wo; int y = (idx / wo) % ho; int c = idx / (wo * ho);
    float py = fminf(fmaxf(0.5f * y - 0.25f, 0.f), (float)(hi - 1));
    float px = fminf(fmaxf(0.5f * x - 0.25f, 0.f), (float)(wi - 1));
    int y0 = (int)py; int x0 = (int)px;
    int y1 = min(y0 + 1, hi - 1); int x1 = min(x0 + 1, wi - 1);
    float dy = py - y0, dx = px - x0;
    const float* ip = in + (i64)c * hi * wi;
    float v = (1.f - dy) * ((1.f - dx) * ip[y0 * wi + x0] + dx * ip[y0 * wi + x1]) +
              dy * ((1.f - dx) * ip[y1 * wi + x0] + dx * ip[y1 * wi + x1]);
    out[idx] = 2.f * v;
}

// ---------------------------------------------------------------- implicit-warp attention
__global__ __launch_bounds__(128) void attn_k(
    const float* __restrict__ prop, i64 pbs, i64 pcs,
    const float* __restrict__ cur,
    const float* __restrict__ flows, int fidx,
    const float* __restrict__ wq_t, const float* __restrict__ wq_b,
    const float* __restrict__ wk_t, const float* __restrict__ wk_b,
    const float* __restrict__ wv_t, const float* __restrict__ wv_b,
    const float* __restrict__ wo_t, const float* __restrict__ wo_b,
    float* __restrict__ outp, i64 obs, i64 ocs,
    short* __restrict__ tf5, int slot)
{
    __shared__ float s_q[8][128];
    __shared__ float s_k[8][4][128];
    __shared__ float s_v[8][4][128];
    __shared__ float s_att[8][4][8];
    __shared__ float s_dx[8], s_dy[8];
    __shared__ int s_nx[8][2], s_ny[8][2];
    const int tid = threadIdx.x;
    const int b = blockIdx.y;
    const int p0 = blockIdx.x * 8;

    if (tid < 8) {
        int p = p0 + tid;
        int gx = p & 63, gy = p >> 6;
        float fx = flows[((i64)(b * 6 + fidx) * 2) * HW + p];
        float fy = flows[((i64)(b * 6 + fidx) * 2 + 1) * HW + p];
        float sx = gx + fx, sy = gy + fy;
        float fxf = floorf(sx), fyf = floorf(sy);
        s_dx[tid] = sx - fxf; s_dy[tid] = sy - fyf;
        s_nx[tid][0] = (int)fminf(fmaxf(fxf, 0.f), 63.f);
        s_nx[tid][1] = (int)fminf(fmaxf(fxf + 1.f, 0.f), 63.f);
        s_ny[tid][0] = (int)fminf(fmaxf(fyf, 0.f), 63.f);
        s_ny[tid][1] = (int)fminf(fmaxf(fyf + 1.f, 0.f), 63.f);
    }
    __syncthreads();

    const int c = tid;
    const int qd = c >> 5;
    const float om = exp2f(-6.643856189774724f * (float)(c & 31) * (1.f / 32.f));

#pragma unroll
    for (int px = 0; px < 8; ++px) {
        int p = p0 + px;
        float dx = s_dx[px], dy = s_dy[px];
        float argq = ((qd < 2) ? dx : dy) * om;
        float peq = (qd & 1) ? __cosf(argq) : __sinf(argq);
        s_q[px][c] = cur[((i64)b * CH + c) * HW + p] + peq;
#pragma unroll
        for (int nb = 0; nb < 4; ++nb) {
            int ox = nb & 1, oy = nb >> 1;
            float g = prop[(i64)b * pbs + (i64)c * pcs + s_ny[px][oy] * 64 + s_nx[px][ox]];
            float rel = (qd < 2) ? ((float)ox - dx) : ((float)oy - dy);
            float arg = rel * om;
            float pe = (qd & 1) ? __cosf(arg) : __sinf(arg);
            s_k[px][nb][c] = g + pe;
            s_v[px][nb][c] = g;
        }
    }
    __syncthreads();

    {
        float qa[8];
#pragma unroll
        for (int i = 0; i < 8; ++i) qa[i] = 0.f;
        for (int j = 0; j < 128; j += 4) {
            float w0 = wq_t[(j    ) * 128 + tid];
            float w1 = wq_t[(j + 1) * 128 + tid];
            float w2 = wq_t[(j + 2) * 128 + tid];
            float w3 = wq_t[(j + 3) * 128 + tid];
#pragma unroll
            for (int px = 0; px < 8; ++px) {
                const float4 x = *(const float4*)&s_q[px][j];
                qa[px] = fmaf(w0, x.x, fmaf(w1, x.y, fmaf(w2, x.z, fmaf(w3, x.w, qa[px]))));
            }
        }
        __syncthreads();
        float bq = wq_b[tid];
#pragma unroll
        for (int px = 0; px < 8; ++px) s_q[px][tid] = qa[px] + bq;
        __syncthreads();
    }
    {
        float ka[8][4];
#pragma unroll
        for (int px = 0; px < 8; ++px)
#pragma unroll
            for (int nb = 0; nb < 4; ++nb) ka[px][nb] = 0.f;
        for (int j = 0; j < 128; j += 4) {
            float w0 = wk_t[(j    ) * 128 + tid];
            float w1 = wk_t[(j + 1) * 128 + tid];
            float w2 = wk_t[(j + 2) * 128 + tid];
            float w3 = wk_t[(j + 3) * 128 + tid];
#pragma unroll
            for (int px = 0; px < 8; ++px)
#pragma unroll
                for (int nb = 0; nb < 4; ++nb) {
                    const float4 x = *(const float4*)&s_k[px][nb][j];
                    ka[px][nb] = fmaf(w0, x.x, fmaf(w1, x.y, fmaf(w2, x.z, fmaf(w3, x.w, ka[px][nb]))));
                }
        }
        __syncthreads();
        float bk = wk_b[tid];
#pragma unroll
        for (int px = 0; px < 8; ++px)
#pragma unroll
            for (int nb = 0; nb < 4; ++nb) s_k[px][nb][tid] = ka[px][nb] + bk;
        __syncthreads();
    }
    {
        float va[8][4];
#pragma unroll
        for (int px = 0; px < 8; ++px)
#pragma unroll
            for (int nb = 0; nb < 4; ++nb) va[px][nb] = 0.f;
        for (int j = 0; j < 128; j += 4) {
            float w0 = wv_t[(j    ) * 128 + tid];
            float w1 = wv_t[(j + 1) * 128 + tid];
            float w2 = wv_t[(j + 2) * 128 + tid];
            float w3 = wv_t[(j + 3) * 128 + tid];
#pragma unroll
            for (int px = 0; px < 8; ++px)
#pragma unroll
                for (int nb = 0; nb < 4; ++nb) {
                    const float4 x = *(const float4*)&s_v[px][nb][j];
                    va[px][nb] = fmaf(w0, x.x, fmaf(w1, x.y, fmaf(w2, x.z, fmaf(w3, x.w, va[px][nb]))));
                }
        }
        __syncthreads();
        float bv = wv_b[tid];
#pragma unroll
        for (int px = 0; px < 8; ++px)
#pragma unroll
            for (int nb = 0; nb < 4; ++nb) s_v[px][nb][tid] = va[px][nb] + bv;
        __syncthreads();
    }
#pragma unroll
    for (int it = 0; it < 2; ++it) {
        int item = it * 128 + tid;
        int px = item >> 5, nb = (item >> 3) & 3, h = item & 7;
        const float* qp = &s_q[px][h * 16];
        const float* kp = &s_k[px][nb][h * 16];
        float s = 0.f;
#pragma unroll
        for (int dd = 0; dd < 16; dd += 4) {
            float4 aa = *(const float4*)&qp[dd];
            float4 bb = *(const float4*)&kp[dd];
            s += aa.x * bb.x + aa.y * bb.y + aa.z * bb.z + aa.w * bb.w;
        }
        s_att[px][nb][h] = s * 0.25f;
    }
    __syncthreads();
    if (tid < 64) {
        int px = tid >> 3, h = tid & 7;
        float l0 = s_att[px][0][h], l1 = s_att[px][1][h], l2 = s_att[px][2][h], l3 = s_att[px][3][h];
        float m = fmaxf(fmaxf(l0, l1), fmaxf(l2, l3));
        float e0 = __expf(l0 - m), e1 = __expf(l1 - m), e2 = __expf(l2 - m), e3 = __expf(l3 - m);
        float inv = 1.f / (e0 + e1 + e2 + e3);
        s_att[px][0][h] = e0 * inv; s_att[px][1][h] = e1 * inv;
        s_att[px][2][h] = e2 * inv; s_att[px][3][h] = e3 * inv;
    }
    __syncthreads();
    {
        int h = tid >> 4;
        float ov[8];
#pragma unroll
        for (int px = 0; px < 8; ++px) {
            ov[px] = s_att[px][0][h] * s_v[px][0][tid] + s_att[px][1][h] * s_v[px][1][tid] +
                     s_att[px][2][h] * s_v[px][2][tid] + s_att[px][3][h] * s_v[px][3][tid];
        }
        __syncthreads();
#pragma unroll
        for (int px = 0; px < 8; ++px) s_q[px][tid] = ov[px];
        __syncthreads();
    }
    {
        float oa[8];
#pragma unroll
        for (int i = 0; i < 8; ++i) oa[i] = 0.f;
        for (int j = 0; j < 128; j += 4) {
            float w0 = wo_t[(j    ) * 128 + tid];
            float w1 = wo_t[(j + 1) * 128 + tid];
            float w2 = wo_t[(j + 2) * 128 + tid];
            float w3 = wo_t[(j + 3) * 128 + tid];
#pragma unroll
            for (int px = 0; px < 8; ++px) {
                const float4 x = *(const float4*)&s_q[px][j];
                oa[px] = fmaf(w0, x.x, fmaf(w1, x.y, fmaf(w2, x.z, fmaf(w3, x.w, oa[px]))));
            }
        }
        float bo = wo_b[tid];
#pragma unroll
        for (int px = 0; px < 8; ++px) {
            float v = oa[px] + bo;
            outp[(i64)b * obs + (i64)tid * ocs + (p0 + px)] = v;
            tf5[(((i64)(b * 7 + slot)) * HW + (p0 + px)) * 128 + tid] = bf16r(v);
        }
    }
}

// ---------------------------------------------------------------- generic linear (dt-proj only)
__global__ void linear_k(
    const float* __restrict__ X, i64 xb, i64 xl, i64 xk, int kmajor,
    const float* __restrict__ Wt, const float* __restrict__ bias,
    float* __restrict__ Y, int Lr, int K, int O, int act)
{
    extern __shared__ float sx[];
    const int tid = threadIdx.x;
    const int r0 = blockIdx.x * 16;
    const int b = r0 / Lr; const int l0 = r0 - b * Lr;
    const int stride = K + 4;
    for (int idx = tid; idx < 16 * K; idx += blockDim.x) {
        int p, k;
        if (kmajor) { k = idx >> 4; p = idx & 15; }
        else { p = idx / K; k = idx - p * K; }
        sx[p * stride + k] = X[(i64)b * xb + (i64)(l0 + p) * xl + (i64)k * xk];
    }
    __syncthreads();
    if (tid < O) {
        float acc[16];
#pragma unroll
        for (int i = 0; i < 16; ++i) acc[i] = 0.f;
        for (int j = 0; j < K; j += 4) {
            float w0 = Wt[(i64)(j    ) * O + tid];
            float w1 = Wt[(i64)(j + 1) * O + tid];
            float w2 = Wt[(i64)(j + 2) * O + tid];
            float w3 = Wt[(i64)(j + 3) * O + tid];
#pragma unroll
            for (int p = 0; p < 16; ++p) {
                const float4 x = *(const float4*)&sx[p * stride + j];
                acc[p] = fmaf(w0, x.x, fmaf(w1, x.y, fmaf(w2, x.z, fmaf(w3, x.w, acc[p]))));
            }
        }
        float bv = bias ? bias[tid] : 0.f;
#pragma unroll
        for (int p = 0; p < 16; ++p) {
            float v = acc[p] + bv;
            if (act == 1) v = fmaxf(v, 0.f) + log1pf(expf(-fabsf(v)));
            Y[(i64)(r0 + p) * O + tid] = v;
        }
    }
}

// ---------------------------------------------------------------- mamba causal conv1d + silu (+bf16 out)
__global__ void conv1d_k(const float* __restrict__ xz, const float* __restrict__ cw,
                         const float* __restrict__ cb, float* __restrict__ xs,
                         short* __restrict__ xsb)
{
    i64 idx = (i64)blockIdx.x * blockDim.x + threadIdx.x;
    if (idx >= (i64)NB * LSEQ * 128) return;
    int d = (int)(idx & 127);
    i64 r = idx >> 7;
    i64 l = r % LSEQ;
    float v = cb[d] + cw[d * 3 + 2] * xz[r * 256 + d];
    if (l >= 1) v += cw[d * 3 + 1] * xz[(r - 1) * 256 + d];
    if (l >= 2) v += cw[d * 3    ] * xz[(r - 2) * 256 + d];
    float sv = v / (1.f + expf(-v));
    xs[r * 128 + d] = sv;
    xsb[r * 128 + d] = bf16r(sv);
}

// ---------------------------------------------------------------- chunked selective scan: d-per-lane, s in regs
#define LOG2E 1.4426950408889634f

__global__ __launch_bounds__(128) void scan1_k(
    const float* __restrict__ dtb, const float* __restrict__ xsb,
    const float* __restrict__ dbc, const float* __restrict__ Alog,
    float* __restrict__ HEND, float* __restrict__ SDT)
{
    const int d = threadIdx.x;
    const int ch = blockIdx.x, b = blockIdx.y;
    const i64 lbase = (i64)b * LSEQ + (i64)ch * LCHUNK;
    float a2[16];
    {
        const float4* ap = (const float4*)(Alog + d * 16);
#pragma unroll
        for (int i = 0; i < 4; ++i) {
            float4 av = ap[i];
            a2[i * 4 + 0] = -expf(av.x) * LOG2E;
            a2[i * 4 + 1] = -expf(av.y) * LOG2E;
            a2[i * 4 + 2] = -expf(av.z) * LOG2E;
            a2[i * 4 + 3] = -expf(av.w) * LOG2E;
        }
    }
    float h[16];
#pragma unroll
    for (int i = 0; i < 16; ++i) h[i] = 0.f;
    float sdt = 0.f;
    for (int t = 0; t < LCHUNK; ++t) {
        i64 l = lbase + t;
        float dtv = dtb[l * 128 + d];
        float xsv = xsb[l * 128 + d];
        const float4* Bp = (const float4*)(dbc + l * 40 + 8);
        float4 B0 = Bp[0], B1 = Bp[1], B2 = Bp[2], B3 = Bp[3];
        float dtxs = dtv * xsv;
        float bs[16] = {B0.x, B0.y, B0.z, B0.w, B1.x, B1.y, B1.z, B1.w,
                        B2.x, B2.y, B2.z, B2.w, B3.x, B3.y, B3.z, B3.w};
#pragma unroll
        for (int s = 0; s < 16; ++s)
            h[s] = fmaf(exp2f(dtv * a2[s]), h[s], dtxs * bs[s]);
        sdt += dtv;
    }
    i64 cb = (i64)b * NCHUNK + ch;
#pragma unroll
    for (int s = 0; s < 16; ++s) HEND[(cb * 16 + s) * 128 + d] = h[s];
    SDT[cb * 128 + d] = sdt;
}

// HH holds HEND on entry, HSTART on exit (in-place; read-before-write per element)
__global__ void scan2_k(float* __restrict__ HH, const float* __restrict__ SDT,
                        const float* __restrict__ Alog)
{
    int idx = blockIdx.x * 256 + threadIdx.x;   // 4096 = NB*16*128
    int b = idx >> 11, s = (idx >> 7) & 15, d = idx & 127;
    float a2 = -expf(Alog[d * 16 + s]) * LOG2E;
    float hs = 0.f;
    for (int ch = 0; ch < NCHUNK; ++ch) {
        i64 cb = (i64)b * NCHUNK + ch;
        i64 base = (cb * 16 + s) * 128 + d;
        float he = HH[base];
        HH[base] = hs;
        hs = fmaf(exp2f(SDT[cb * 128 + d] * a2), hs, he);
    }
}

__global__ __launch_bounds__(128) void scan3_k(
    const float* __restrict__ dtb, const float* __restrict__ xsb,
    const float* __restrict__ dbc, const float* __restrict__ Alog,
    const float* __restrict__ HSTART,
    const float* __restrict__ xz, const float* __restrict__ Dp,
    short* __restrict__ yb)
{
    const int d = threadIdx.x;
    const int ch = blockIdx.x, b = blockIdx.y;
    const i64 lbase = (i64)b * LSEQ + (i64)ch * LCHUNK;
    float a2[16];
    {
        const float4* ap = (const float4*)(Alog + d * 16);
#pragma unroll
        for (int i = 0; i < 4; ++i) {
            float4 av = ap[i];
            a2[i * 4 + 0] = -expf(av.x) * LOG2E;
            a2[i * 4 + 1] = -expf(av.y) * LOG2E;
            a2[i * 4 + 2] = -expf(av.z) * LOG2E;
            a2[i * 4 + 3] = -expf(av.w) * LOG2E;
        }
    }
    const i64 cb = (i64)b * NCHUNK + ch;
    float h[16];
#pragma unroll
    for (int s = 0; s < 16; ++s) h[s] = HSTART[(cb * 16 + s) * 128 + d];
    const float dp = Dp[d];
    for (int t = 0; t < LCHUNK; ++t) {
        i64 l = lbase + t;
        float dtv = dtb[l * 128 + d];
        float xsv = xsb[l * 128 + d];
        const float4* Bp = (const float4*)(dbc + l * 40 + 8);
        float4 B0 = Bp[0], B1 = Bp[1], B2 = Bp[2], B3 = Bp[3];
        const float4* Cp = (const float4*)(dbc + l * 40 + 24);
        float4 C0 = Cp[0], C1 = Cp[1], C2 = Cp[2], C3 = Cp[3];
        float dtxs = dtv * xsv;
        float bs[16] = {B0.x, B0.y, B0.z, B0.w, B1.x, B1.y, B1.z, B1.w,
                        B2.x, B2.y, B2.z, B2.w, B3.x, B3.y, B3.z, B3.w};
        float cs[16] = {C0.x, C0.y, C0.z, C0.w, C1.x, C1.y, C1.z, C1.w,
                        C2.x, C2.y, C2.z, C2.w, C3.x, C3.y, C3.z, C3.w};
#pragma unroll
        for (int s = 0; s < 16; ++s)
            h[s] = fmaf(exp2f(dtv * a2[s]), h[s], dtxs * bs[s]);
        float y0 = fmaf(h[3], cs[3], fmaf(h[2], cs[2], fmaf(h[1], cs[1], h[0] * cs[0])));
        float y1 = fmaf(h[7], cs[7], fmaf(h[6], cs[6], fmaf(h[5], cs[5], h[4] * cs[4])));
        float y2 = fmaf(h[11], cs[11], fmaf(h[10], cs[10], fmaf(h[9], cs[9], h[8] * cs[8])));
        float y3 = fmaf(h[15], cs[15], fmaf(h[14], cs[14], fmaf(h[13], cs[13], h[12] * cs[12])));
        float yc = (y0 + y1) + (y2 + y3);
        float zv = xz[l * 256 + 128 + d];
        float yf = (yc + xsv * dp) * (zv / (1.f + expf(-zv)));
        yb[l * 128 + d] = bf16r(yf);
    }
}

// ================================================================ host
extern "C" void kernel_launch(void* const* d_in, const int* in_sizes, int n_in,
                              void* d_out, int out_size, void* d_ws, size_t ws_size,
                              hipStream_t stream) {
    (void)in_sizes; (void)n_in; (void)out_size; (void)ws_size;
    const float* Lin[7];
    for (int i = 0; i < 7; ++i) Lin[i] = (const float*)d_in[i];
    const float* conv_rec_w = (const float*)d_in[7];
    const float* conv_rec_b = (const float*)d_in[8];
    const float* conv3_w    = (const float*)d_in[9];
    const float* conv3_b    = (const float*)d_in[10];
    const float* conv1x1_w  = (const float*)d_in[11];
    const float* conv1x1_b  = (const float*)d_in[12];
    const float* conv13_w   = (const float*)d_in[13];
    const float* conv13_b   = (const float*)d_in[14];
    const float* wq_w = (const float*)d_in[15]; const float* wq_b = (const float*)d_in[16];
    const float* wk_w = (const float*)d_in[17]; const float* wk_b = (const float*)d_in[18];
    const float* wv_w = (const float*)d_in[19]; const float* wv_b = (const float*)d_in[20];
    const float* wo_w = (const float*)d_in[21]; const float* wo_b = (const float*)d_in[22];
    const float* m_in_w    = (const float*)d_in[23];
    const float* m_conv_w  = (const float*)d_in[24];
    const float* m_conv_b  = (const float*)d_in[25];
    const float* m_xproj_w = (const float*)d_in[26];
    const float* m_dt_w    = (const float*)d_in[27];
    const float* m_dt_b    = (const float*)d_in[28];
    const float* m_Alog    = (const float*)d_in[29];
    const float* m_D       = (const float*)d_in[30];
    const float* m_out_w   = (const float*)d_in[31];
    const float* spy1_w = (const float*)d_in[32]; const float* spy1_b = (const float*)d_in[33];
    const float* spy2_w = (const float*)d_in[34]; const float* spy2_b = (const float*)d_in[35];
    float* out = (float*)d_out;
    float* W = (float*)d_ws;

    Ptr7 P7; for (int i = 0; i < 7; ++i) P7.p[i] = Lin[i];

    // -------- workspace layout (floats). Aliasing map (lifetime-disjoint, audited):
    //   XSB(bf16)  -> TIN region   (TIN dead after conv3; XSB written at conv1d)
    //   TF5(bf16)  -> DT region    (TF5 dead after in-proj; DT written at dt-proj)
    //   YB (bf16)  -> FEATS region (FEATS dead after attn chain; YB written at scan3)
    //   MO2(bf16)  -> XZ region    (XZ dead after scan3; MO2 written at out-proj)
    //   HSTART     -> HEND in-place (scan2 reads element before overwriting it)
    i64 off = 0;
    float* FEATS  = W + off; off += (i64)TF * NB * CH * HW;       // 7.34M
    float* FEATS5 = W + off; off += (i64)NB * CH * TF * HW;       // 7.34M
    float* XZ     = W + off; off += (i64)NB * LSEQ * 256;         // 14.68M
    float* XS     = W + off; off += (i64)NB * LSEQ * 128;         // 7.34M
    float* DBC    = W + off; off += (i64)NB * LSEQ * 40;          // 2.29M
    float* DT     = W + off; off += (i64)NB * LSEQ * 128;         // 7.34M (shares with TF5)
    float* WQ_T = W + off; off += 16384;
    float* WK_T = W + off; off += 16384;
    float* WV_T = W + off; off += 16384;
    float* WO_T = W + off; off += 16384;
    float* MDT_T  = W + off; off += 128 * 8;
    float* LQS  = W + off; off += (i64)NB * TF * 3 * HW;
    float* P1_0 = W + off; off += 12 * 3 * HW;
    float* P2_0 = W + off; off += 12 * 3 * HW;
    float* P1_1 = W + off; off += 12 * 3 * 1024;
    float* P2_1 = W + off; off += 12 * 3 * 1024;
    float* P1_2 = W + off; off += 12 * 3 * 256;
    float* P2_2 = W + off; off += 12 * 3 * 256;
    float* FLOW2 = W + off; off += 12 * 2 * 256;
    float* FLOW1 = W + off; off += 12 * 2 * 1024;
    float* FLOW0 = W + off; off += 12 * 2 * HW;
    float* INP = W + off; off += 12 * 8 * HW;
    float* HHB = W + off; off += 12 * 32 * HW;
    float* HEND   = W + off; off += (i64)NB * NCHUNK * 16 * 128;  // 1.84M; becomes HSTART in scan2
    float* SDT    = W + off; off += (i64)NB * NCHUNK * 128;
    // -------- bf16 region (shorts)
    short* SBASE = (short*)(W + off);
    i64 soff = 0;
    short* TIN    = SBASE + soff; soff += (i64)14 * HW * 128;
    short* TFEATS = SBASE + soff; soff += (i64)14 * HW * 128;
    short* TOUT   = SBASE + soff; soff += (i64)NB * HW * 128;
    short* WB3    = SBASE + soff; soff += (i64)9 * 2 * 8192;
    short* WB13   = SBASE + soff; soff += (i64)9 * 4 * 8192;
    short* WGIN   = SBASE + soff; soff += 2 * 2 * 8192;
    short* WGXP   = SBASE + soff; soff += 2 * 1 * 8192;
    short* WGOUT  = SBASE + soff; soff += 2 * 1 * 8192;
    short* WG11   = SBASE + soff; soff += 14 * 1 * 8192;
    // aliases
    short* XSB = TIN;
    short* TF5 = (short*)DT;
    short* YB  = (short*)FEATS;
    short* MO2 = (short*)XZ;
    float* HSTART = HEND;

    // -------- weight transposes / preps
    auto T = [&](const float* src, float* dst, int R, int Cc) {
        transpose_k<<<cdiv((i64)R * Cc, 256), 256, 0, stream>>>(src, dst, R, Cc);
    };
    T(wq_w, WQ_T, 128, 128); T(wk_w, WK_T, 128, 128);
    T(wv_w, WV_T, 128, 128); T(wo_w, WO_T, 128, 128);
    T(m_dt_w, MDT_T, 128, 8);
    wprep_k<<<cdiv(9 * 2 * 8192, 256), 256, 0, stream>>>(conv3_w, WB3, 128, 2);
    wprep_k<<<cdiv(9 * 4 * 8192, 256), 256, 0, stream>>>(conv13_w, WB13, 256, 4);
    wgprep_k<<<cdiv(2 * 2 * 8192, 256), 256, 0, stream>>>(m_in_w,    WGIN,  128, 256, 2, 0, 2 * 2 * 8192);
    wgprep_k<<<cdiv(2 * 1 * 8192, 256), 256, 0, stream>>>(m_xproj_w, WGXP,  128, 40,  1, 0, 2 * 1 * 8192);
    wgprep_k<<<cdiv(2 * 1 * 8192, 256), 256, 0, stream>>>(m_out_w,   WGOUT, 128, 128, 1, 0, 2 * 1 * 8192);
    wgprep_k<<<cdiv(14 * 8192, 256), 256, 0, stream>>>(conv1x1_w, WG11, 896, 128, 1, 1, 14 * 8192);
    tprep_k<<<dim3(32, 14), 256, 0, stream>>>(P7, TIN);

    // -------- conv_rec (fp32) -> LQS
    convrec_k<<<dim3(16, 14), 256, 0, stream>>>(P7, conv_rec_w, conv_rec_b, LQS);

    // -------- conv3 (MFMA) -> FEATS fp32 + TFEATS bf16
    {
        Ptr7 none; for (int i = 0; i < 7; ++i) none.p[i] = nullptr;
        convmfma_k<<<dim3(32, 14), 256, 0, stream>>>(
            TIN, nullptr, 2, 2, WB3, conv3_b, none, 0, FEATS, TFEATS, 1);
    }

    // -------- spynet
    copy_pyr_k<<<cdiv(12 * 3 * HW, 256), 256, 0, stream>>>(LQS, P1_0, 0);
    copy_pyr_k<<<cdiv(12 * 3 * HW, 256), 256, 0, stream>>>(LQS, P2_0, 1);
    avgpool_k<<<cdiv(36 * 32 * 32, 256), 256, 0, stream>>>(P1_0, P1_1, 36, 64, 64);
    avgpool_k<<<cdiv(36 * 32 * 32, 256), 256, 0, stream>>>(P2_0, P2_1, 36, 64, 64);
    avgpool_k<<<cdiv(36 * 16 * 16, 256), 256, 0, stream>>>(P1_1, P1_2, 36, 32, 32);
    avgpool_k<<<cdiv(36 * 16 * 16, 256), 256, 0, stream>>>(P2_1, P2_2, 36, 32, 32);
    hipMemsetAsync(FLOW2, 0, 12 * 2 * 256 * sizeof(float), stream);

    struct Lvl { float *p1, *p2, *fl; int hw_; };
    Lvl lv[3] = { {P1_2, P2_2, FLOW2, 16}, {P1_1, P2_1, FLOW1, 32}, {P1_0, P2_0, FLOW0, 64} };
    for (int li = 0; li < 3; ++li) {
        int hl = lv[li].hw_;
        int hw = hl * hl;
        int tiles = (hl / 16) * (hl / 16);
        build_inp_k<<<cdiv(12 * hw, 256), 256, 0, stream>>>(lv[li].p1, lv[li].p2, lv[li].fl, INP, hl, hl);
        conv3x3_k<<<dim3(tiles, 2, 12), 256, 0, stream>>>(
            INP, 8, (i64)8 * hw, nullptr, 0, 0, spy1_w, spy1_b, 32, hl, hl,
            nullptr, 0, HHB, (i64)32 * hw, 1);
        conv3x3_k<<<dim3(tiles, 1, 12), 256, 0, stream>>>(
            HHB, 32, (i64)32 * hw, nullptr, 0, 0, spy2_w, spy2_b, 2, hl, hl,
            lv[li].fl, (i64)2 * hw, lv[li].fl, (i64)2 * hw, 0);
        if (li < 2) {
            int ho = hl * 2;
            resize_flow_k<<<cdiv(12 * 2 * ho * ho, 256), 256, 0, stream>>>(lv[li].fl, lv[li + 1].fl, hl, hl);
        }
    }

    // -------- propagation: TF5 slot0 + attn slots 1..6 (writes FEATS5 fp32 + TF5 bf16)
    slot0_k<<<dim3(32, NB), 256, 0, stream>>>(FEATS + 6LL * NB * CH * HW, TF5);
    for (int i = 1; i <= 6; ++i) {
        int fidx = 6 - i;
        const float* cur = FEATS + (i64)fidx * NB * CH * HW;
        const float* prop; i64 pbs, pcs;
        if (i == 1) { prop = FEATS + 6LL * NB * CH * HW; pbs = (i64)CH * HW; pcs = HW; }
        else { prop = FEATS5 + (i64)(i - 1) * HW; pbs = (i64)CH * TF * HW; pcs = (i64)TF * HW; }
        attn_k<<<dim3(512, 2), 128, 0, stream>>>(
            prop, pbs, pcs, cur, FLOW0, fidx,
            WQ_T, wq_b, WK_T, wk_b, WV_T, wv_b, WO_T, wo_b,
            FEATS5 + (i64)i * HW, (i64)CH * TF * HW, (i64)TF * HW,
            TF5, i);
    }

    // -------- mamba
    // in-proj: XZ[l][256] = TF5[l][128] @ m_in_w^T   (bf16 MFMA)
    gemm_k<<<dim3(448, 2), 256, 0, stream>>>(TF5, 128, 2, 2, WGIN, nullptr, 128, XZ, 256, nullptr, 0);
    conv1d_k<<<cdiv((i64)NB * LSEQ * 128, 256), 256, 0, stream>>>(XZ, m_conv_w, m_conv_b, XS, XSB);
    // x-proj: DBC[l][40] = XSB[l][128] @ m_xproj_w^T
    gemm_k<<<dim3(448, 1), 256, 0, stream>>>(XSB, 128, 2, 1, WGXP, nullptr, 40, DBC, 40, nullptr, 0);
    // dt-proj (fp32, K=8, softplus)
    linear_k<<<(NB * LSEQ) / 16, 128, 16 * (8 + 4) * 4, stream>>>(
        DBC, (i64)LSEQ * 40, 40, 1, 0, MDT_T, m_dt_b, DT, LSEQ, 8, 128, 1);
    // selective scan (3 phases)
    scan1_k<<<dim3(NCHUNK, NB), 128, 0, stream>>>(DT, XS, DBC, m_Alog, HEND, SDT);
    scan2_k<<<16, 256, 0, stream>>>(HEND, SDT, m_Alog);
    scan3_k<<<dim3(NCHUNK, NB), 128, 0, stream>>>(DT, XS, DBC, m_Alog, HSTART, XZ, m_D, YB);
    // out-proj: MO2[b*HW+p][896] (regrouped) = YB[l][128] @ m_out_w^T
    gemm_k<<<dim3(448, 1), 256, 0, stream>>>(YB, 128, 2, 1, WGOUT, nullptr, 128, nullptr, 0, MO2, 1);
    // conv1x1: TOUT[b*HW+p][128] = lrelu(MO2 @ w1^T + b1)
    gemm_k<<<dim3(64, 1), 256, 0, stream>>>(MO2, 896, 14, 1, WG11, conv1x1_b, 128, nullptr, 0, TOUT, 2);

    // -------- conv13 (MFMA) + residual -> d_out
    convmfma_k<<<dim3(32, 14), 256, 0, stream>>>(
        TFEATS, TOUT, 4, 2, WB13, conv13_b, P7, 1, out, nullptr, 1);
}